// Round 13
// baseline (416.719 us; speedup 1.0000x reference)
//
#include <hip/hip_runtime.h>

typedef unsigned short u16;
typedef unsigned int u32;

__device__ __forceinline__ float b2f(u16 v) { return __uint_as_float((u32)v << 16); }
__device__ __forceinline__ float lopart(u32 u) { return __uint_as_float(u << 16); }
__device__ __forceinline__ float hipart(u32 u) { return __uint_as_float(u & 0xffff0000u); }
__device__ __forceinline__ u16 f2b(float f) {
  u32 u = __float_as_uint(f);
  u32 r = u + 0x7fffu + ((u >> 16) & 1u);
  return (u16)(r >> 16);
}
__device__ __forceinline__ u32 pk2(float a, float b) {
  return (u32)f2b(a) | ((u32)f2b(b) << 16);
}
__device__ __forceinline__ u32 cvtpk(float lo, float hi) {
  u32 r;
  asm("v_cvt_pk_bf16_f32 %0, %1, %2" : "=v"(r) : "v"(lo), "v"(hi));
  return r;
}
__device__ __forceinline__ float rd(const void* p, int i, bool BF) {
  return BF ? b2f(((const u16*)p)[i]) : ((const float*)p)[i];
}

struct Ptrs { const void* p[29]; };

typedef __attribute__((ext_vector_type(8))) short short8;
typedef __attribute__((ext_vector_type(4))) float floatx4;

// ---------------- K-prep: fused cvt + A-pack + folded-weight prep + stats zero ----------------
__global__ __launch_bounds__(256) void k_prep(Ptrs ps, float* __restrict__ Wf,
                                              u16* __restrict__ Abf, float* __restrict__ WT,
                                              u16* __restrict__ WBu, float* __restrict__ stats) {
  bool BF = ((*(const u32*)ps.p[25]) & 0xffffu) != 0;
  int blk = blockIdx.x, tid = threadIdx.x;
  if (blk < 256) {
    int j = blk * 256 + tid;
    if (j >= 65322) return;
    const int SZ[27] = {1024,32,2048,64,12288,64,12288,64,4096,64,4096,64,2048,32,
                        10240,64,60,6,32,500,16000,36,36,6,6,32,32};
    int t = 0, off = 0;
#pragma unroll
    for (int k = 0; k < 27; ++k) {
      if (t == k && j >= off + SZ[k]) { off += SZ[k]; t = k + 1; }
    }
    Wf[j] = rd(ps.p[2 + t], j - off, BF);
  } else if (blk < 1280) {
    int i = (blk - 256) * 256 + tid;
    int r = i >> 9, v = i & 511;
    bool in = (r < 500) && (v < 500);
    u16 o = 0;
    if (in) o = BF ? ((const u16*)ps.p[1])[r * 500 + v] : f2b(((const float*)ps.p[1])[r * 500 + v]);
    Abf[i] = o;
  } else if (blk < 1366) {
    int i = (blk - 1280) * 256 + tid;
    const void* p2  = ps.p[2];
    const void* p4  = ps.p[4];
    const void* p5  = ps.p[5];
    const void* p6  = ps.p[6];
    const void* p7  = ps.p[7];
    const void* p8  = ps.p[8];
    const void* p9  = ps.p[9];
    const void* p10 = ps.p[10];
    const void* p11 = ps.p[11];
    const void* p12 = ps.p[12];
    const void* p13 = ps.p[13];
    const void* p14 = ps.p[14];
    const void* p15 = ps.p[15];
    const void* p16 = ps.p[16];
    if (i < 1024) {
      WT[i] = rd(p2, (i & 31) * 32 + (i >> 5), BF);
    } else if (i < 7168) {
      int j2 = i - 1024;
      int o = j2 & 63, ct = j2 >> 6;
      int c = ct / 3, tap = ct - c * 3;
      float sq = 0.f, sk = 0.f;
      for (int i2 = 0; i2 < 64; ++i2) {
        float te = rd(p4, i2 * 32 + c, BF);
        sq += rd(p6, o * 192 + i2 * 3 + tap, BF) * te;
        sk += rd(p8, o * 192 + i2 * 3 + tap, BF) * te;
      }
      ((u32*)WT)[i] = pk2(sq, sk);
    } else if (i < 7552) {
      int j2 = i - 7168;
      int f = j2 >> 6, o = j2 & 63;
      const void* pw = (f & 1) ? p8 : p6;
      float S0 = 0.f, S1 = 0.f, S2 = 0.f;
      for (int i2 = 0; i2 < 64; ++i2) {
        float tb = rd(p5, i2, BF);
        S0 += rd(pw, o * 192 + i2 * 3 + 0, BF) * tb;
        S1 += rd(pw, o * 192 + i2 * 3 + 1, BF) * tb;
        S2 += rd(pw, o * 192 + i2 * 3 + 2, BF) * tb;
      }
      float r;
      if (f == 0)      r = rd(p7, o, BF) + S0 + S1 + S2;
      else if (f == 1) r = rd(p9, o, BF) + S0 + S1 + S2;
      else if (f < 4)  r = S0;
      else             r = S2;
      WT[i] = r;
    } else if (i < 9600) {
      int j2 = i - 7552;
      int c = j2 >> 6, o = j2 & 63;
      float s = 0.f;
      for (int i2 = 0; i2 < 64; ++i2)
        s += rd(p10, o * 64 + i2, BF) * rd(p4, i2 * 32 + c, BF);
      WT[i] = s;
    } else if (i < 9664) {
      int o = i - 9600;
      float s = rd(p11, o, BF);
      for (int i2 = 0; i2 < 64; ++i2)
        s += rd(p10, o * 64 + i2, BF) * rd(p5, i2, BF);
      WT[i] = s;
    } else if (i < 11712) {
      int j2 = i - 9664;
      int jj = j2 >> 5, c = j2 & 31;
      float s = 0.f;
      for (int o2 = 0; o2 < 64; ++o2)
        s += rd(p14, c * 64 + o2, BF) * rd(p12, o2 * 64 + jj, BF);
      WT[i] = s;
    } else if (i < 11744) {
      int c = i - 11712;
      float s = rd(p15, c, BF);
      for (int o2 = 0; o2 < 64; ++o2)
        s += rd(p14, c * 64 + o2, BF) * rd(p13, o2, BF);
      WT[i] = s;
    } else if (i < 21984) {
      int j2 = i - 11744;
      int j = j2 & 7, lanev = (j2 >> 3) & 63, ct = (j2 >> 9) & 3, kt = j2 >> 11;
      int qv = lanev >> 4, lnv = lanev & 15;
      int o = ct * 16 + lnv, k = kt * 32 + qv * 8 + j;
      WBu[j2] = f2b(rd(p16, o * 160 + k, BF));
    }
  } else {
    if (tid < 64) stats[tid] = 0.f;
  }
}

// ---------------- K0m: MFMA A2 = A @ A (bf16 in/out, fp32 accumulate) ----------------
__global__ __launch_bounds__(256, 4) void k_a2m(const u16* __restrict__ Abf,
                                                u16* __restrict__ A2bf) {
  __shared__ u32 blsT[8192];     // [c][k-pair] swizzled (32 KB), c = local col
  int tid = threadIdx.x;
  int c0 = blockIdx.x * 32;
  for (int i = tid; i < 8192; i += 256) {
    int c = i & 31, h = i >> 5;
    int r0 = 2 * h;
    u32 lo = Abf[r0 * 512 + c0 + c];
    u32 hi = Abf[(r0 + 1) * 512 + c0 + c];
    blsT[c * 256 + (((h & 0xFC) ^ ((c & 15) << 2)) | (h & 3))] = lo | (hi << 16);
  }
  __syncthreads();
  int lane = tid & 63, wave = tid >> 6;
  int q = lane >> 4, ln = lane & 15;
  int rbase = blockIdx.y * 64 + wave * 16;
  const u32* Au = (const u32*)Abf;
  int arow = (rbase + ln) * 256;
  union F8 { u32 u[4]; short8 s; };
  floatx4 acc[2] = {{0.f,0.f,0.f,0.f},{0.f,0.f,0.f,0.f}};
  for (int c2 = 0; c2 < 16; ++c2) {
    int hb = c2 * 16 + q * 4;
    F8 af;
#pragma unroll
    for (int i2 = 0; i2 < 4; ++i2) af.u[i2] = Au[arow + hb + i2];
#pragma unroll
    for (int t2 = 0; t2 < 2; ++t2) {
      int c = t2 * 16 + ln;
      int baseT = c * 256 + (hb ^ ((c & 15) << 2));
      F8 bf;
#pragma unroll
      for (int i2 = 0; i2 < 4; ++i2) bf.u[i2] = blsT[baseT + i2];
      acc[t2] = __builtin_amdgcn_mfma_f32_16x16x32_bf16(af.s, bf.s, acc[t2], 0, 0, 0);
    }
  }
#pragma unroll
  for (int t2 = 0; t2 < 2; ++t2) {
#pragma unroll
    for (int i2 = 0; i2 < 4; ++i2) {
      int r = rbase + q * 4 + i2;
      A2bf[r * 512 + c0 + t2 * 16 + ln] = f2b(acc[t2][i2]);
    }
  }
}

// ---------------- K1: frontend (folded), one (b,n) pair per WAVE, zero block barriers ----------------
__global__ __launch_bounds__(256, 7) void k_front3(
    const void* __restrict__ xraw, const void* __restrict__ g1, const float* __restrict__ WT,
    const float* __restrict__ c1B,
    float* __restrict__ h3x, float* __restrict__ res6)
{
  __shared__ __align__(16) float arena[4][1440];
  int tid = threadIdx.x;
  int wave = tid >> 6, lane = tid & 63;
  float* Aw = arena[wave];
  int pair = blockIdx.x * 4 + wave;
  int b = pair / 500, n = pair - b * 500;

  const float* c1T  = WT;
  const u32*   qkF  = (const u32*)(WT + 1024);
  const float* bCq  = WT + 7168;
  const float* bCk  = WT + 7232;
  const float* bE0q = WT + 7296;
  const float* bE0k = WT + 7360;
  const float* bE2q = WT + 7424;
  const float* bE2k = WT + 7488;
  const float* vT   = WT + 7552;
  const float* bvp  = WT + 9600;
  const float* otT  = WT + 9664;
  const float* botp = WT + 11712;

  // ---- x -> LDS rows [c*12 + t] (convert at point of use)
  {
    bool BF = ((*(const u32*)g1) & 0xffffu) != 0;
    int c0 = lane >> 1, hf = (lane & 1) * 5;
    int base = ((b * 32 + c0) * 500 + n) * 10 + hf;
    float* dst = Aw + c0 * 12 + hf;
    if (BF) {
      const u16* xp = (const u16*)xraw + base;
#pragma unroll
      for (int k2 = 0; k2 < 5; ++k2) dst[k2] = b2f(xp[k2]);
    } else {
      const float* xp = (const float*)xraw + base;
#pragma unroll
      for (int k2 = 0; k2 < 5; ++k2) dst[k2] = xp[k2];
    }
  }
  __builtin_amdgcn_wave_barrier();

  int cl = lane & 31, th = lane >> 5;

  // ---- residual: lane=(c, th), 3 time outputs each
  {
    float r0 = c1B[cl], r1 = r0, r2 = r0;
#pragma unroll 4
    for (int i = 0; i < 32; ++i) {
      float w = c1T[i * 32 + cl];
      const float* xr = Aw + i * 12 + 4 + th * 3;
      r0 += w * xr[0]; r1 += w * xr[1]; r2 += w * xr[2];
    }
    float* rp = res6 + ((b * 32 + cl) * 500 + n) * 6 + th * 3;
    rp[0] = r0; rp[1] = r1; rp[2] = r2;
  }

  // ---- q,k,v directly from x: lane = o; 66 FMA per c-iteration, broadcast x rows
  float qr[10], kr[10], vr[10];
  {
    float cq = bCq[lane], ck = bCk[lane], bv = bvp[lane];
#pragma unroll
    for (int t = 0; t < 10; ++t) { qr[t] = cq; kr[t] = ck; vr[t] = bv; }
    qr[0] -= bE0q[lane]; kr[0] -= bE0k[lane];
    qr[9] -= bE2q[lane]; kr[9] -= bE2k[lane];
    const u32* qp0 = qkF + lane;
    const float* vp0 = vT + lane;
#pragma unroll 2
    for (int c = 0; c < 32; ++c) {
      const float* xr = Aw + c * 12;
      float4 ha = *(const float4*)xr;
      float4 hb = *(const float4*)(xr + 4);
      float2 hc = *(const float2*)(xr + 8);
      u32 u0 = qp0[c * 192];
      u32 u1 = qp0[c * 192 + 64];
      u32 u2 = qp0[c * 192 + 128];
      float wv = vp0[c * 64];
      float q0 = lopart(u0), q1 = lopart(u1), q2 = lopart(u2);
      float k0 = hipart(u0), k1 = hipart(u1), k2v = hipart(u2);
      float hh[10] = {ha.x, ha.y, ha.z, ha.w, hb.x, hb.y, hb.z, hb.w, hc.x, hc.y};
#pragma unroll
      for (int t = 0; t < 10; ++t) { float c_ = hh[t]; qr[t] += q1 * c_; kr[t] += k1 * c_; vr[t] += wv * c_; }
#pragma unroll
      for (int t = 1; t < 10; ++t) { float c_ = hh[t - 1]; qr[t] += q0 * c_; kr[t] += k0 * c_; }
#pragma unroll
      for (int t = 0; t < 9; ++t) { float c_ = hh[t + 1]; qr[t] += q2 * c_; kr[t] += k2v * c_; }
    }
  }
  __builtin_amdgcn_wave_barrier();
  // spill q and k as bf16 pairs (stride 5 u32 each)
  {
    u32* qu = (u32*)Aw + lane * 5;
    u32* ku = (u32*)Aw + 320 + lane * 5;
#pragma unroll
    for (int m = 0; m < 5; ++m) {
      qu[m] = cvtpk(qr[2 * m], qr[2 * m + 1]);
      ku[m] = cvtpk(kr[2 * m], kr[2 * m + 1]);
    }
  }
  __builtin_amdgcn_wave_barrier();

  // ---- scores + softmax: 80 (head,row) rows over 2 passes; P -> [640,1440)
  {
    const u32* qb = (const u32*)Aw;
    const u32* kb = (const u32*)Aw + 320;
#pragma unroll
    for (int pass = 0; pass < 2; ++pass) {
      int row = pass * 64 + lane;
      if (row < 80) {
        int h8 = (row / 10) * 8, r = row - (row / 10) * 10;
        int rm = r >> 1, rs = r & 1;
        float sv[10];
#pragma unroll
        for (int s = 0; s < 10; ++s) sv[s] = 0.f;
#pragma unroll 2
        for (int d = 0; d < 8; ++d) {
          int jj = h8 + d;
          u32 qu = qb[jj * 5 + rm];
          float qv = rs ? hipart(qu) : lopart(qu);
          const u32* kp2 = kb + jj * 5;
          u32 ka0 = kp2[0], ka1 = kp2[1], ka2 = kp2[2], ka3 = kp2[3], ka4 = kp2[4];
          sv[0] += qv * lopart(ka0); sv[1] += qv * hipart(ka0);
          sv[2] += qv * lopart(ka1); sv[3] += qv * hipart(ka1);
          sv[4] += qv * lopart(ka2); sv[5] += qv * hipart(ka2);
          sv[6] += qv * lopart(ka3); sv[7] += qv * hipart(ka3);
          sv[8] += qv * lopart(ka4); sv[9] += qv * hipart(ka4);
        }
        const float sc_ = 0.35355339059327373f;
        float mx = sv[0];
#pragma unroll
        for (int s = 1; s < 10; ++s) mx = fmaxf(mx, sv[s]);
        float tot = 0.f, ev[10];
#pragma unroll
        for (int s = 0; s < 10; ++s) { ev[s] = __expf((sv[s] - mx) * sc_); tot += ev[s]; }
        float inv = 1.f / tot;
        float* pp = Aw + 640 + row * 10;
#pragma unroll
        for (int s = 0; s < 10; ++s) pp[s] = ev[s] * inv;
      }
    }
  }
  __builtin_amdgcn_wave_barrier();

  // ---- PV: lane = j (head h=j>>3), v in regs, P broadcast per 8-lane group; o -> [0,768)
  {
    const float* pb = Aw + 640 + (lane >> 3) * 100;
    float orr[10];
#pragma unroll
    for (int t = 0; t < 10; ++t) {
      const float* pr = pb + t * 10;
      float a = 0.f;
#pragma unroll
      for (int s = 0; s < 10; ++s) a += pr[s] * vr[s];
      orr[t] = a;
    }
    float* op = Aw + lane * 12;
    *(float4*)op       = make_float4(orr[0], orr[1], orr[2], orr[3]);
    *(float4*)(op + 4) = make_float4(orr[4], orr[5], orr[6], orr[7]);
    *(float2*)(op + 8) = make_float2(orr[8], orr[9]);
  }
  __builtin_amdgcn_wave_barrier();

  // ---- fused lino+te2 + h3x store: lane = (c, th), 5 t's each
  {
    float bt2 = botp[cl];
    float a5[5];
#pragma unroll
    for (int k2 = 0; k2 < 5; ++k2) a5[k2] = bt2;
    const float* tp0 = otT + cl;
    const float* base = Aw + th * 5;
#pragma unroll 2
    for (int j = 0; j < 64; ++j) {
      float w = tp0[j * 32];
      const float* lp = base + j * 12;
#pragma unroll
      for (int k2 = 0; k2 < 5; ++k2) a5[k2] += w * lp[k2];
    }
    int t0 = th * 5;
#pragma unroll
    for (int k2 = 0; k2 < 5; ++k2)
      h3x[((b * 10 + t0 + k2) * 500 + n) * 32 + cl] = a5[k2];
  }
}

// ---------------- K2: MFMA z1 = A @ XT, z2 = A2 @ XT ----------------
// STAGE-AMORTIZED: grid (160,4); each block stages XT once (B-frags are row-chunk
// invariant) then loops 2 row-chunks of 64 rows. Staging redundancy 8x -> 4x.
__global__ __launch_bounds__(256, 4) void k_z12m(const float* __restrict__ h3x,
    const u16* __restrict__ Abf, const u16* __restrict__ A2bf,
    float* __restrict__ z1x, float* __restrict__ z2x) {
  __shared__ u32 xlsT[8192];     // [n][half-row] pairs, swizzled (32 KB)
  int tid = threadIdx.x, bt = blockIdx.x, yh = blockIdx.y;
  const float* src = h3x + bt * 16000;
  for (int i = tid; i < 8192; i += 256) {
    int n = i & 31, h = i >> 5;
    int r0 = 2 * h;
    float v0 = (r0 < 500) ? src[r0 * 32 + n] : 0.f;
    float v1 = (r0 + 1 < 500) ? src[(r0 + 1) * 32 + n] : 0.f;
    xlsT[n * 256 + (((h & 0xFC) ^ ((n & 15) << 2)) | (h & 3))] = cvtpk(v0, v1);
  }
  __syncthreads();
  int lane = tid & 63, wave = tid >> 6;
  int q = lane >> 4, ln = lane & 15;
  const u32* Au = (const u32*)Abf;
  const u32* A2u = (const u32*)A2bf;
  union F8 { u32 u[4]; short8 s; };
  int outb = bt * 16000;
  for (int chunk = 0; chunk < 2; ++chunk) {
    int rbase = yh * 128 + chunk * 64 + wave * 16;
    int arow = (rbase + ln) * 256;
    floatx4 acc1[2] = {{0.f,0.f,0.f,0.f},{0.f,0.f,0.f,0.f}};
    floatx4 acc2[2] = {{0.f,0.f,0.f,0.f},{0.f,0.f,0.f,0.f}};
    for (int c2 = 0; c2 < 16; ++c2) {
      int hb = c2 * 16 + q * 4;         // aligned half-row base for this quad's k-slice
      F8 a1f, a2f;
#pragma unroll
      for (int i2 = 0; i2 < 4; ++i2) {
        a1f.u[i2] = Au[arow + hb + i2];
        a2f.u[i2] = A2u[arow + hb + i2];
      }
#pragma unroll
      for (int t2 = 0; t2 < 2; ++t2) {
        int n = t2 * 16 + ln;
        int baseT = n * 256 + (hb ^ ((n & 15) << 2));
        F8 bf;
#pragma unroll
        for (int i2 = 0; i2 < 4; ++i2) bf.u[i2] = xlsT[baseT + i2];
        acc1[t2] = __builtin_amdgcn_mfma_f32_16x16x32_bf16(a1f.s, bf.s, acc1[t2], 0, 0, 0);
        acc2[t2] = __builtin_amdgcn_mfma_f32_16x16x32_bf16(a2f.s, bf.s, acc2[t2], 0, 0, 0);
      }
    }
#pragma unroll
    for (int t2 = 0; t2 < 2; ++t2) {
#pragma unroll
      for (int i2 = 0; i2 < 4; ++i2) {
        int r = rbase + q * 4 + i2;
        if (r < 500) {
          z1x[outb + r * 32 + t2 * 16 + ln] = acc1[t2][i2];
          z2x[outb + r * 32 + t2 * 16 + ln] = acc2[t2][i2];
        }
      }
    }
  }
}

// ---------------- K3: MFMA fused attention: out = softmax(K K^T / sqrt(32)) @ V ----------------
// STAGE-AMORTIZED: grid (160,2); each block stages K (stride-20, resident) AND V^T
// (z12m layout, resident) ONCE, then loops 8 row-chunks of 32 reusing the wave-pair
// schedule (acc[16]/wave, deferred normalization, per-wave pch). LDS 76.8 KB -> 2/CU;
// all 320 blocks co-resident (single generation).
__global__ __launch_bounds__(256, 2) void k_attn2(const float* __restrict__ keys,
                                                  const float* __restrict__ vals,
                                                  float* __restrict__ outp) {
  __shared__ u32 kls[10240];       // K rows stride-20 (40 KB), resident
  __shared__ u32 vls[8192];        // V^T z12m swizzled (32 KB), resident
  __shared__ u32 aux[1216];        // pch 4x272 @0 (reused as zex); smx @1088; sms @1152
  int tid = threadIdx.x, bt = blockIdx.x, yh = blockIdx.y;
  const float* kb = keys + bt * 16000;
  const float* vb = vals + bt * 16000;
  for (int i = tid; i < 8192; i += 256) {
    int r = i >> 4, cu = i & 15;
    float2 g = make_float2(0.f, 0.f);
    if (r < 500) g = *(const float2*)(kb + r * 32 + cu * 2);
    kls[r * 20 + cu] = cvtpk(g.x, g.y);
    int n = i & 31, h = i >> 5;
    int r0 = 2 * h;
    float v0 = (r0 < 500) ? vb[r0 * 32 + n] : 0.f;
    float v1 = (r0 + 1 < 500) ? vb[(r0 + 1) * 32 + n] : 0.f;
    vls[n * 256 + (((h & 0xFC) ^ ((n & 15) << 2)) | (h & 3))] = cvtpk(v0, v1);
  }
  __syncthreads();
  int lane = tid & 63, wave = tid >> 6;
  int q = lane >> 4, ln = lane & 15;
  int wrow = wave >> 1, ch = wave & 1;
  float* smx = (float*)(aux + 1088);
  float* sms = (float*)(aux + 1152);
  u32* myp = aux + wave * 272;
  float* zex = (float*)aux;
  u16* pw = (u16*)myp;
  union F8 { u32 u[4]; short8 s; };
  const float sc = 0.17677669529663687f;
  int outb = bt * 16000;
  for (int chunk = 0; chunk < 8; ++chunk) {
    int rbase = yh * 256 + chunk * 32 + wrow * 16;
    F8 af;
    {
      int r = rbase + ln;
      int wbase = r * 20 + q * 4;
#pragma unroll
      for (int i2 = 0; i2 < 4; ++i2)
        af.u[i2] = kls[wbase + i2];
    }
    floatx4 acc[16];
#pragma unroll
    for (int ctl = 0; ctl < 16; ++ctl) {
      int r2 = (ch * 16 + ctl) * 16 + ln;
      int wb2 = r2 * 20 + q * 4;
      F8 bf;
#pragma unroll
      for (int i2 = 0; i2 < 4; ++i2)
        bf.u[i2] = kls[wb2 + i2];
      acc[ctl] = __builtin_amdgcn_mfma_f32_16x16x32_bf16(af.s, bf.s,
                (floatx4){0.f, 0.f, 0.f, 0.f}, 0, 0, 0);
    }
    if (ch == 1 && ln >= 4) {
#pragma unroll
      for (int i2 = 0; i2 < 4; ++i2) acc[15][i2] = -1e30f;   // cols >= 500
    }
    float m[4];
#pragma unroll
    for (int i2 = 0; i2 < 4; ++i2) {
      float mm = -1e30f;
#pragma unroll
      for (int ctl = 0; ctl < 16; ++ctl) mm = fmaxf(mm, acc[ctl][i2]);
#pragma unroll
      for (int d = 1; d < 16; d <<= 1) mm = fmaxf(mm, __shfl_xor(mm, d));
      m[i2] = mm;
    }
    if (ln == 0) {
#pragma unroll
      for (int i2 = 0; i2 < 4; ++i2) smx[wave * 16 + q * 4 + i2] = m[i2];
    }
    __syncthreads();   // (A) smx visible; also orders prior chunk's zex reads
    float sp[4];
#pragma unroll
    for (int i2 = 0; i2 < 4; ++i2) {
      float mm = fmaxf(m[i2], smx[(wave ^ 1) * 16 + q * 4 + i2]);
      float s = 0.f;
#pragma unroll
      for (int ctl = 0; ctl < 16; ++ctl) {
        float e = __expf((acc[ctl][i2] - mm) * sc);
        acc[ctl][i2] = e; s += e;
      }
#pragma unroll
      for (int d = 1; d < 16; d <<= 1) s += __shfl_xor(s, d);
      sp[i2] = s;
    }
    if (ln == 0) {
#pragma unroll
      for (int i2 = 0; i2 < 4; ++i2) sms[wave * 16 + q * 4 + i2] = sp[i2];
    }
    __syncthreads();   // (B) sms visible
    float inv[4];
#pragma unroll
    for (int i2 = 0; i2 < 4; ++i2)
      inv[i2] = 1.f / (sp[i2] + sms[(wave ^ 1) * 16 + q * 4 + i2]);
    floatx4 zacc[2] = {{0.f,0.f,0.f,0.f},{0.f,0.f,0.f,0.f}};
    for (int c2l = 0; c2l < 8; ++c2l) {
#pragma unroll
      for (int t2 = 0; t2 < 2; ++t2) {
        int ctl = c2l * 2 + t2;
#pragma unroll
        for (int i2 = 0; i2 < 4; ++i2)
          pw[(q * 4 + i2) * 34 + t2 * 16 + ln] = f2b(acc[ctl][i2]);
      }
      __builtin_amdgcn_wave_barrier();
      F8 pa;
#pragma unroll
      for (int i2 = 0; i2 < 4; ++i2) pa.u[i2] = myp[ln * 17 + q * 4 + i2];
      int hb = (ch * 8 + c2l) * 16 + q * 4;     // this wave's half-k slice
#pragma unroll
      for (int t2 = 0; t2 < 2; ++t2) {
        int n = t2 * 16 + ln;
        int baseT = n * 256 + (hb ^ ((n & 15) << 2));
        F8 bf;
#pragma unroll
        for (int i2 = 0; i2 < 4; ++i2) bf.u[i2] = vls[baseT + i2];
        zacc[t2] = __builtin_amdgcn_mfma_f32_16x16x32_bf16(pa.s, bf.s, zacc[t2], 0, 0, 0);
      }
      __builtin_amdgcn_wave_barrier();
    }
    __syncthreads();   // (C1) all pch reads done before zex overwrite
    if (ch) {
#pragma unroll
      for (int t2 = 0; t2 < 2; ++t2)
#pragma unroll
        for (int i2 = 0; i2 < 4; ++i2)
          zex[wrow * 544 + (q * 4 + i2) * 34 + t2 * 16 + ln] = zacc[t2][i2];
    }
    __syncthreads();   // (C2) zex visible
    if (!ch) {
#pragma unroll
      for (int t2 = 0; t2 < 2; ++t2) {
#pragma unroll
        for (int i2 = 0; i2 < 4; ++i2) {
          int r = rbase + q * 4 + i2;
          if (r < 500) {
            float vsum = zacc[t2][i2] + zex[wrow * 544 + (q * 4 + i2) * 34 + t2 * 16 + ln];
            outp[outb + r * 32 + t2 * 16 + ln] = vsum * inv[i2];
          }
        }
      }
    }
  }
}

// ---------------- K4: MFMA mlp + gate + fused ct1 -> g2 ----------------
__global__ __launch_bounds__(256, 2) void k_gate(
    const float* __restrict__ h3x, const float* __restrict__ z1x, const float* __restrict__ z2x,
    const float* __restrict__ z3x, const float* __restrict__ z4x,
    const u32* __restrict__ WBq, const float* __restrict__ mlpB,
    const float* __restrict__ ct1W, const float* __restrict__ ct1B,
    float* __restrict__ g2w)
{
  __shared__ u32 wlds[5120];       // 20 KB: 20 B-frags x 64 lanes x 4 u32
  int tid = threadIdx.x;
  for (int i = tid; i < 5120; i += 256) wlds[i] = WBq[i];
  __syncthreads();
  int lane = tid & 63, wave = tid >> 6;
  int q = lane >> 4, ln = lane & 15;
  int b = blockIdx.y;
  int n0 = blockIdx.x * 32 + wave * 8;
  int nA = n0 + (ln & 7);          // A-row n for this lane
  int tAb = ln >> 3;               // A-row t_local (0/1)
  int nD = n0 + (q & 1) * 4;       // D-row n base (n = nD + i)
  int tDb = q >> 1;                // D-row t_local
  float g2a[4][2][6];
#pragma unroll
  for (int i = 0; i < 4; ++i)
#pragma unroll
    for (int ch = 0; ch < 2; ++ch)
#pragma unroll
      for (int s = 0; s < 6; ++s) g2a[i][ch][s] = 0.f;
  float bias[4];
#pragma unroll
  for (int ct = 0; ct < 4; ++ct) bias[ct] = mlpB[ct * 16 + ln];
  union F8 { u32 u[4]; short8 s; };
  for (int tile = 0; tile < 5; ++tile) {
    int tA = tile * 2 + tAb;
    int offA = (((b * 10 + tA) * 500) + nA) * 32 + q * 8;
    floatx4 acc[4];
#pragma unroll
    for (int ct = 0; ct < 4; ++ct) acc[ct] = (floatx4){bias[ct], bias[ct], bias[ct], bias[ct]};
#pragma unroll
    for (int kt = 0; kt < 5; ++kt) {
      const float* sp = kt == 0 ? h3x : kt == 1 ? z1x : kt == 2 ? z2x : kt == 3 ? z3x : z4x;
      float4 a0 = *(const float4*)(sp + offA);
      float4 a1 = *(const float4*)(sp + offA + 4);
      F8 af;
      af.u[0] = cvtpk(a0.x, a0.y);
      af.u[1] = cvtpk(a0.z, a0.w);
      af.u[2] = cvtpk(a1.x, a1.y);
      af.u[3] = cvtpk(a1.z, a1.w);
#pragma unroll
      for (int ct = 0; ct < 4; ++ct) {
        F8 bfr;
        const u32* wp = wlds + (((kt * 4 + ct) << 6) + lane) * 4;
#pragma unroll
        for (int i2 = 0; i2 < 4; ++i2) bfr.u[i2] = wp[i2];
        acc[ct] = __builtin_amdgcn_mfma_f32_16x16x32_bf16(af.s, bfr.s, acc[ct], 0, 0, 0);
      }
    }
    int tD = tile * 2 + tDb;
    float c6[6];
#pragma unroll
    for (int s = 0; s < 6; ++s) c6[s] = ct1W[s * 10 + tD];
#pragma unroll
    for (int i = 0; i < 4; ++i) {
      float e0 = __expf(2.f * acc[0][i]);
      float g0 = ((e0 - 1.f) / (e0 + 1.f)) * (1.f / (1.f + __expf(-acc[2][i])));
      float e1 = __expf(2.f * acc[1][i]);
      float g1 = ((e1 - 1.f) / (e1 + 1.f)) * (1.f / (1.f + __expf(-acc[3][i])));
#pragma unroll
      for (int s = 0; s < 6; ++s) {
        g2a[i][0][s] += g0 * c6[s];
        g2a[i][1][s] += g1 * c6[s];
      }
    }
  }
  // combine even-t (q=0,1) and odd-t (q=2,3) partial sums: lane pair = lane ^ 32
#pragma unroll
  for (int i = 0; i < 4; ++i)
#pragma unroll
    for (int ch = 0; ch < 2; ++ch)
#pragma unroll
      for (int s = 0; s < 6; ++s)
        g2a[i][ch][s] += __shfl_xor(g2a[i][ch][s], 32);
  if (q < 2) {
#pragma unroll
    for (int i = 0; i < 4; ++i) {
      int n = nD + i;
      if (n < 500) {
#pragma unroll
        for (int ch = 0; ch < 2; ++ch) {
          int c = ln + ch * 16;
          float* gp = g2w + ((b * 32 + c) * 500 + n) * 6;
#pragma unroll
          for (int s = 0; s < 6; ++s) gp[s] = g2a[i][ch][s] + ct1B[s];
        }
      }
    }
  }
}

// ---------------- K4b: fused f1 + f2 ----------------
__global__ __launch_bounds__(256) void k_f12(const float* __restrict__ g2w,
                                             const float* __restrict__ tc1W,
                                             const float* __restrict__ c2W,
                                             float* __restrict__ f1w, float* __restrict__ f2w) {
  int blk = blockIdx.x, tid = threadIdx.x;
  if (blk < 188) {
    int i = blk * 256 + tid;
    if (i >= 48000) return;
    int b = i / 3000, rem = i - b * 3000, s = rem / 500, n = rem - s * 500;
    float a = 0.f;
    for (int c = 0; c < 32; ++c) a += g2w[((b * 32 + c) * 500 + n) * 6 + s] * tc1W[c];
    f1w[(b * 6 + s) * 500 + n] = a;
  } else {
    int pb = (blk - 188) * 4 + (tid >> 6);   // 0..511 (b,c) pairs
    int b = pb >> 5, c = pb & 31, lane = tid & 63;
    float acc[6];
#pragma unroll
    for (int t = 0; t < 6; ++t) acc[t] = 0.f;
    for (int n = lane; n < 500; n += 64) {
      float w = c2W[n];
      const float* gp = g2w + ((b * 32 + c) * 500 + n) * 6;
#pragma unroll
      for (int t = 0; t < 6; ++t) acc[t] += w * gp[t];
    }
#pragma unroll
    for (int t = 0; t < 6; ++t)
      for (int off = 32; off; off >>= 1) acc[t] += __shfl_xor(acc[t], off);
    if (lane == 0) {
#pragma unroll
      for (int t = 0; t < 6; ++t) f2w[(b * 32 + c) * 6 + t] = acc[t];
    }
  }
}

// ---------------- K5b: per-b TATT ----------------
__global__ __launch_bounds__(256) void k_tatt(
    const float* __restrict__ f1w, const float* __restrict__ tatw,
    const float* __restrict__ f2w, const float* __restrict__ tatb, const float* __restrict__ tatv,
    float* __restrict__ lg2w)
{
  __shared__ float mid[192];
  __shared__ float lgt[36];
  int b = blockIdx.x, tid = threadIdx.x;
  if (tid < 192) {
    int t = tid >> 5, c = tid & 31;
    float a = 0.f;
    const float* f1p = f1w + (b * 6 + t) * 500;
    for (int n = 0; n < 500; ++n) a += f1p[n] * tatw[n * 32 + c];
    mid[t * 32 + c] = a;
  }
  __syncthreads();
  if (tid < 36) {
    int t = tid / 6, s = tid - t * 6;
    float a = tatb[t * 6 + s];
    for (int c = 0; c < 32; ++c) a += mid[t * 32 + c] * f2w[(b * 32 + c) * 6 + s];
    lgt[t * 6 + s] = 1.f / (1.f + expf(-a));
  }
  __syncthreads();
  if (tid < 36) {
    int p = tid / 6, s = tid - p * 6;
    float a = 0.f;
#pragma unroll
    for (int t2 = 0; t2 < 6; ++t2) a += tatv[p * 6 + t2] * lgt[t2 * 6 + s];
    lg2w[(b * 6 + p) * 6 + s] = a;
  }
}

// ---------------- K5c: BN1 + softmax -> Tc ----------------
__global__ __launch_bounds__(128) void k_coefs(const float* __restrict__ lg2w,
    const float* __restrict__ bn1g, const float* __restrict__ bn1b, float* __restrict__ tcw) {
  __shared__ float mu[6], iv[6], gg[6], bb[6];
  int tid = threadIdx.x;
  if (tid < 6) {
    float s = 0.f, sq = 0.f;
    for (int b = 0; b < 16; ++b)
      for (int q = 0; q < 6; ++q) {
        float v = lg2w[(b * 6 + q) * 6 + tid];
        s += v; sq += v * v;
      }
    float m = s / 96.f;
    mu[tid] = m;
    iv[tid] = rsqrtf(sq / 96.f - m * m + 1e-5f);
    gg[tid] = bn1g[tid]; bb[tid] = bn1b[tid];
  }
  __syncthreads();
  for (int idx = tid; idx < 96; idx += 128) {
    int b = idx / 6, q = idx - b * 6;
    float v[6], mx = -1e30f;
#pragma unroll
    for (int l = 0; l < 6; ++l) {
      v[l] = (lg2w[(b * 6 + q) * 6 + l] - mu[l]) * iv[l] * gg[l] + bb[l];
      mx = fmaxf(mx, v[l]);
    }
    float tot = 0.f;
#pragma unroll
    for (int l = 0; l < 6; ++l) { v[l] = expf(v[l] - mx); tot += v[l]; }
    float inv = 1.f / tot;
#pragma unroll
    for (int l = 0; l < 6; ++l) tcw[(b * 6 + l) * 6 + q] = v[l] * inv;
  }
}

// ---------------- K6a: xo = leaky(g2@Tc)+res6, per-c sum/sumsq ----------------
__global__ __launch_bounds__(256) void k_xo(const float* __restrict__ g2w,
    const float* __restrict__ res6, const float* __restrict__ tcw,
    float* __restrict__ xow, float* __restrict__ stats) {
  __shared__ float Tcl[36];
  __shared__ float redS[32][8], redQ[32][8];
  int b = blockIdx.x, chunk = blockIdx.y, tid = threadIdx.x;
  if (tid < 36) Tcl[tid] = tcw[b * 36 + tid];
  __syncthreads();
  int c = tid & 31, sub = tid >> 5;
  int n0 = chunk * 50;
  float s = 0.f, sq = 0.f;
  for (int idx = sub; idx < 300; idx += 8) {
    int nl = idx / 6, q = idx - nl * 6;
    int n = n0 + nl;
    int base = ((b * 32 + c) * 500 + n) * 6;
    const float* gp = g2w + base;
    float xv = 0.f;
#pragma unroll
    for (int l = 0; l < 6; ++l) xv += gp[l] * Tcl[l * 6 + q];
    xv = xv > 0.f ? xv : 0.01f * xv;
    xv += res6[base + q];
    xow[base + q] = xv;
    s += xv; sq += xv * xv;
  }
  redS[c][sub] = s; redQ[c][sub] = sq;
  __syncthreads();
  if (sub == 0) {
    float ts = 0.f, tq = 0.f;
#pragma unroll
    for (int k = 0; k < 8; ++k) { ts += redS[c][k]; tq += redQ[c][k]; }
    atomicAdd(&stats[c], ts);
    atomicAdd(&stats[32 + c], tq);
  }
}

// ---------------- K6b: BN2 normalize -> FP32 out ----------------
__global__ __launch_bounds__(256) void k_out(const float* __restrict__ xow,
    const float* __restrict__ stats, const float* __restrict__ g2c, const float* __restrict__ b2c,
    float* __restrict__ out) {
  int base = (blockIdx.x * 256 + threadIdx.x) * 4;
#pragma unroll
  for (int k = 0; k < 4; ++k) {
    int i = base + k;
    int c = (i / 3000) & 31;
    float m = stats[c] * (1.f / 48000.f);
    float var = stats[32 + c] * (1.f / 48000.f) - m * m;
    out[i] = (xow[i] - m) * rsqrtf(var + 1e-5f) * g2c[c] + b2c[c];
  }
}

extern "C" void kernel_launch(void* const* d_in, const int* in_sizes, int n_in,
                              void* d_out, int out_size, void* d_ws, size_t ws_size,
                              hipStream_t stream)
{
  (void)in_sizes; (void)out_size;

  float* ws = (float*)d_ws;
  float* Af   = ws;                 // 250,000 (unused; layout kept)
  float* Wf   = Af + 250000;        // 65,536 (65,322 used)
  float* A2   = Wf + 65536;         // 250,000 (unused; layout kept)
  float* h3x  = A2 + 250000;        // 2,560,000 (B,T,N,32)
  float* z1x  = h3x + 2560000;
  float* z2x  = z1x + 2560000;
  float* z3x  = z2x + 2560000;
  float* z4x  = z3x + 2560000;
  float* res6 = z4x + 2560000;      // 1,536,000
  float* g2w  = res6 + 1536000;     // 1,536,000
  float* f1w  = g2w + 1536000;      // 48,000
  float* f2w  = f1w + 48000;        // 3,072
  float* lg2w = f2w + 3072;         // 576
  float* tcw  = lg2w + 576;         // 576
  float* stats= tcw + 576;          // 64
  float* xow  = z1x;                // reuse z1 region after k_gate
  u16*   Abf  = (u16*)g2w;          // 512x512 bf16 A pack (g2w region dead until k_gate)
  u16*   A2bf = (u16*)(g2w + 131072); // 512x512 bf16 A2 pack
  float* WTp  = g2w + 262144;       // 11,744 folded-weight pack (dead before k_gate)
  u16*   WBu  = (u16*)f1w;          // 10,240 u16 mlpW B-frag pack (f1w region dead until k_f12)
  if (ws_size < (size_t)16489952 * sizeof(float)) return;  // workspace guard

  // converted-weight offsets inside Wf (cumulative over dict inputs 2..28)
  const float* c1B  = Wf + 1024;
  const float* mlpB = Wf + 48512;
  const float* ct1W = Wf + 48576;
  const float* ct1B = Wf + 48636;
  const float* tc1W = Wf + 48642;
  const float* tc2W = Wf + 48674;
  const float* tatw = Wf + 49174;
  const float* tatb = Wf + 65174;
  const float* tatv = Wf + 65210;
  const float* bn1g = Wf + 65246;
  const float* bn1b = Wf + 65252;
  const float* bn2g = Wf + 65258;
  const float* bn2b = Wf + 65290;

  Ptrs ps;
  for (int i = 0; i < 29; ++i) ps.p[i] = (i < n_in) ? d_in[i] : d_in[0];

  k_prep <<<dim3(1367),    256, 0, stream>>>(ps, Wf, Abf, WTp, WBu, stats);
  k_a2m  <<<dim3(16, 8),   256, 0, stream>>>(Abf, A2bf);
  k_front3<<<dim3(2000),   256, 0, stream>>>(ps.p[0], ps.p[25], WTp, c1B, h3x, res6);
  k_z12m <<<dim3(160, 4),  256, 0, stream>>>(h3x, Abf, A2bf, z1x, z2x);
  k_attn2<<<dim3(160, 2),  256, 0, stream>>>(h3x, h3x, z3x);
  k_attn2<<<dim3(160, 2),  256, 0, stream>>>(h3x, z3x, z4x);
  k_gate <<<dim3(16, 16),  256, 0, stream>>>(h3x, z1x, z2x, z3x, z4x,
                                             (const u32*)WBu, mlpB, ct1W, ct1B, g2w);
  k_f12  <<<dim3(316),     256, 0, stream>>>(g2w, tc1W, tc2W, f1w, f2w);
  k_tatt <<<dim3(16),      256, 0, stream>>>(f1w, tatw, f2w, tatb, tatv, lg2w);
  k_coefs<<<dim3(1),       128, 0, stream>>>(lg2w, bn1g, bn1b, tcw);
  k_xo   <<<dim3(16, 10),  256, 0, stream>>>(g2w, res6, tcw, xow, stats);
  k_out  <<<dim3(1500),    256, 0, stream>>>(xow, stats, bn2g, bn2b, (float*)d_out);
}

// Round 14
// 401.060 us; speedup vs baseline: 1.0390x; 1.0390x over previous
//
#include <hip/hip_runtime.h>

typedef unsigned short u16;
typedef unsigned int u32;

__device__ __forceinline__ float b2f(u16 v) { return __uint_as_float((u32)v << 16); }
__device__ __forceinline__ float lopart(u32 u) { return __uint_as_float(u << 16); }
__device__ __forceinline__ float hipart(u32 u) { return __uint_as_float(u & 0xffff0000u); }
__device__ __forceinline__ u16 f2b(float f) {
  u32 u = __float_as_uint(f);
  u32 r = u + 0x7fffu + ((u >> 16) & 1u);
  return (u16)(r >> 16);
}
__device__ __forceinline__ u32 pk2(float a, float b) {
  return (u32)f2b(a) | ((u32)f2b(b) << 16);
}
__device__ __forceinline__ u32 cvtpk(float lo, float hi) {
  u32 r;
  asm("v_cvt_pk_bf16_f32 %0, %1, %2" : "=v"(r) : "v"(lo), "v"(hi));
  return r;
}
__device__ __forceinline__ float rd(const void* p, int i, bool BF) {
  return BF ? b2f(((const u16*)p)[i]) : ((const float*)p)[i];
}

struct Ptrs { const void* p[29]; };

typedef __attribute__((ext_vector_type(8))) short short8;
typedef __attribute__((ext_vector_type(4))) float floatx4;

// ---------------- K-prep: fused cvt + A-pack + folded-weight prep + stats zero ----------------
__global__ __launch_bounds__(256) void k_prep(Ptrs ps, float* __restrict__ Wf,
                                              u16* __restrict__ Abf, float* __restrict__ WT,
                                              u16* __restrict__ WBu, float* __restrict__ stats) {
  bool BF = ((*(const u32*)ps.p[25]) & 0xffffu) != 0;
  int blk = blockIdx.x, tid = threadIdx.x;
  if (blk < 256) {
    int j = blk * 256 + tid;
    if (j >= 65322) return;
    const int SZ[27] = {1024,32,2048,64,12288,64,12288,64,4096,64,4096,64,2048,32,
                        10240,64,60,6,32,500,16000,36,36,6,6,32,32};
    int t = 0, off = 0;
#pragma unroll
    for (int k = 0; k < 27; ++k) {
      if (t == k && j >= off + SZ[k]) { off += SZ[k]; t = k + 1; }
    }
    Wf[j] = rd(ps.p[2 + t], j - off, BF);
  } else if (blk < 1280) {
    int i = (blk - 256) * 256 + tid;
    int r = i >> 9, v = i & 511;
    bool in = (r < 500) && (v < 500);
    u16 o = 0;
    if (in) o = BF ? ((const u16*)ps.p[1])[r * 500 + v] : f2b(((const float*)ps.p[1])[r * 500 + v]);
    Abf[i] = o;
  } else if (blk < 1366) {
    int i = (blk - 1280) * 256 + tid;
    const void* p2  = ps.p[2];
    const void* p4  = ps.p[4];
    const void* p5  = ps.p[5];
    const void* p6  = ps.p[6];
    const void* p7  = ps.p[7];
    const void* p8  = ps.p[8];
    const void* p9  = ps.p[9];
    const void* p10 = ps.p[10];
    const void* p11 = ps.p[11];
    const void* p12 = ps.p[12];
    const void* p13 = ps.p[13];
    const void* p14 = ps.p[14];
    const void* p15 = ps.p[15];
    const void* p16 = ps.p[16];
    if (i < 1024) {
      WT[i] = rd(p2, (i & 31) * 32 + (i >> 5), BF);
    } else if (i < 7168) {
      int j2 = i - 1024;
      int o = j2 & 63, ct = j2 >> 6;
      int c = ct / 3, tap = ct - c * 3;
      float sq = 0.f, sk = 0.f;
      for (int i2 = 0; i2 < 64; ++i2) {
        float te = rd(p4, i2 * 32 + c, BF);
        sq += rd(p6, o * 192 + i2 * 3 + tap, BF) * te;
        sk += rd(p8, o * 192 + i2 * 3 + tap, BF) * te;
      }
      ((u32*)WT)[i] = pk2(sq, sk);
    } else if (i < 7552) {
      int j2 = i - 7168;
      int f = j2 >> 6, o = j2 & 63;
      const void* pw = (f & 1) ? p8 : p6;
      float S0 = 0.f, S1 = 0.f, S2 = 0.f;
      for (int i2 = 0; i2 < 64; ++i2) {
        float tb = rd(p5, i2, BF);
        S0 += rd(pw, o * 192 + i2 * 3 + 0, BF) * tb;
        S1 += rd(pw, o * 192 + i2 * 3 + 1, BF) * tb;
        S2 += rd(pw, o * 192 + i2 * 3 + 2, BF) * tb;
      }
      float r;
      if (f == 0)      r = rd(p7, o, BF) + S0 + S1 + S2;
      else if (f == 1) r = rd(p9, o, BF) + S0 + S1 + S2;
      else if (f < 4)  r = S0;
      else             r = S2;
      WT[i] = r;
    } else if (i < 9600) {
      int j2 = i - 7552;
      int c = j2 >> 6, o = j2 & 63;
      float s = 0.f;
      for (int i2 = 0; i2 < 64; ++i2)
        s += rd(p10, o * 64 + i2, BF) * rd(p4, i2 * 32 + c, BF);
      WT[i] = s;
    } else if (i < 9664) {
      int o = i - 9600;
      float s = rd(p11, o, BF);
      for (int i2 = 0; i2 < 64; ++i2)
        s += rd(p10, o * 64 + i2, BF) * rd(p5, i2, BF);
      WT[i] = s;
    } else if (i < 11712) {
      int j2 = i - 9664;
      int jj = j2 >> 5, c = j2 & 31;
      float s = 0.f;
      for (int o2 = 0; o2 < 64; ++o2)
        s += rd(p14, c * 64 + o2, BF) * rd(p12, o2 * 64 + jj, BF);
      WT[i] = s;
    } else if (i < 11744) {
      int c = i - 11712;
      float s = rd(p15, c, BF);
      for (int o2 = 0; o2 < 64; ++o2)
        s += rd(p14, c * 64 + o2, BF) * rd(p13, o2, BF);
      WT[i] = s;
    } else if (i < 21984) {
      int j2 = i - 11744;
      int j = j2 & 7, lanev = (j2 >> 3) & 63, ct = (j2 >> 9) & 3, kt = j2 >> 11;
      int qv = lanev >> 4, lnv = lanev & 15;
      int o = ct * 16 + lnv, k = kt * 32 + qv * 8 + j;
      WBu[j2] = f2b(rd(p16, o * 160 + k, BF));
    }
  } else {
    if (tid < 64) stats[tid] = 0.f;
  }
}

// ---------------- K0m: MFMA A2 = A @ A (bf16 in/out, fp32 accumulate) ----------------
__global__ __launch_bounds__(256, 4) void k_a2m(const u16* __restrict__ Abf,
                                                u16* __restrict__ A2bf) {
  __shared__ u32 blsT[8192];     // [c][k-pair] swizzled (32 KB), c = local col
  int tid = threadIdx.x;
  int c0 = blockIdx.x * 32;
  for (int i = tid; i < 8192; i += 256) {
    int c = i & 31, h = i >> 5;
    int r0 = 2 * h;
    u32 lo = Abf[r0 * 512 + c0 + c];
    u32 hi = Abf[(r0 + 1) * 512 + c0 + c];
    blsT[c * 256 + (((h & 0xFC) ^ ((c & 15) << 2)) | (h & 3))] = lo | (hi << 16);
  }
  __syncthreads();
  int lane = tid & 63, wave = tid >> 6;
  int q = lane >> 4, ln = lane & 15;
  int rbase = blockIdx.y * 64 + wave * 16;
  const u32* Au = (const u32*)Abf;
  int arow = (rbase + ln) * 256;
  union F8 { u32 u[4]; short8 s; };
  floatx4 acc[2] = {{0.f,0.f,0.f,0.f},{0.f,0.f,0.f,0.f}};
  for (int c2 = 0; c2 < 16; ++c2) {
    int hb = c2 * 16 + q * 4;
    F8 af;
#pragma unroll
    for (int i2 = 0; i2 < 4; ++i2) af.u[i2] = Au[arow + hb + i2];
#pragma unroll
    for (int t2 = 0; t2 < 2; ++t2) {
      int c = t2 * 16 + ln;
      int baseT = c * 256 + (hb ^ ((c & 15) << 2));
      F8 bf;
#pragma unroll
      for (int i2 = 0; i2 < 4; ++i2) bf.u[i2] = blsT[baseT + i2];
      acc[t2] = __builtin_amdgcn_mfma_f32_16x16x32_bf16(af.s, bf.s, acc[t2], 0, 0, 0);
    }
  }
#pragma unroll
  for (int t2 = 0; t2 < 2; ++t2) {
#pragma unroll
    for (int i2 = 0; i2 < 4; ++i2) {
      int r = rbase + q * 4 + i2;
      A2bf[r * 512 + c0 + t2 * 16 + ln] = f2b(acc[t2][i2]);
    }
  }
}

// ---------------- K1: frontend (folded), one (b,n) pair per WAVE, zero block barriers ----------------
__global__ __launch_bounds__(256, 7) void k_front3(
    const void* __restrict__ xraw, const void* __restrict__ g1, const float* __restrict__ WT,
    const float* __restrict__ c1B,
    float* __restrict__ h3x, float* __restrict__ res6)
{
  __shared__ __align__(16) float arena[4][1440];
  int tid = threadIdx.x;
  int wave = tid >> 6, lane = tid & 63;
  float* Aw = arena[wave];
  int pair = blockIdx.x * 4 + wave;
  int b = pair / 500, n = pair - b * 500;

  const float* c1T  = WT;
  const u32*   qkF  = (const u32*)(WT + 1024);
  const float* bCq  = WT + 7168;
  const float* bCk  = WT + 7232;
  const float* bE0q = WT + 7296;
  const float* bE0k = WT + 7360;
  const float* bE2q = WT + 7424;
  const float* bE2k = WT + 7488;
  const float* vT   = WT + 7552;
  const float* bvp  = WT + 9600;
  const float* otT  = WT + 9664;
  const float* botp = WT + 11712;

  // ---- x -> LDS rows [c*12 + t] (convert at point of use)
  {
    bool BF = ((*(const u32*)g1) & 0xffffu) != 0;
    int c0 = lane >> 1, hf = (lane & 1) * 5;
    int base = ((b * 32 + c0) * 500 + n) * 10 + hf;
    float* dst = Aw + c0 * 12 + hf;
    if (BF) {
      const u16* xp = (const u16*)xraw + base;
#pragma unroll
      for (int k2 = 0; k2 < 5; ++k2) dst[k2] = b2f(xp[k2]);
    } else {
      const float* xp = (const float*)xraw + base;
#pragma unroll
      for (int k2 = 0; k2 < 5; ++k2) dst[k2] = xp[k2];
    }
  }
  __builtin_amdgcn_wave_barrier();

  int cl = lane & 31, th = lane >> 5;

  // ---- residual: lane=(c, th), 3 time outputs each
  {
    float r0 = c1B[cl], r1 = r0, r2 = r0;
#pragma unroll 4
    for (int i = 0; i < 32; ++i) {
      float w = c1T[i * 32 + cl];
      const float* xr = Aw + i * 12 + 4 + th * 3;
      r0 += w * xr[0]; r1 += w * xr[1]; r2 += w * xr[2];
    }
    float* rp = res6 + ((b * 32 + cl) * 500 + n) * 6 + th * 3;
    rp[0] = r0; rp[1] = r1; rp[2] = r2;
  }

  // ---- q,k,v directly from x: lane = o; 66 FMA per c-iteration, broadcast x rows
  float qr[10], kr[10], vr[10];
  {
    float cq = bCq[lane], ck = bCk[lane], bv = bvp[lane];
#pragma unroll
    for (int t = 0; t < 10; ++t) { qr[t] = cq; kr[t] = ck; vr[t] = bv; }
    qr[0] -= bE0q[lane]; kr[0] -= bE0k[lane];
    qr[9] -= bE2q[lane]; kr[9] -= bE2k[lane];
    const u32* qp0 = qkF + lane;
    const float* vp0 = vT + lane;
#pragma unroll 2
    for (int c = 0; c < 32; ++c) {
      const float* xr = Aw + c * 12;
      float4 ha = *(const float4*)xr;
      float4 hb = *(const float4*)(xr + 4);
      float2 hc = *(const float2*)(xr + 8);
      u32 u0 = qp0[c * 192];
      u32 u1 = qp0[c * 192 + 64];
      u32 u2 = qp0[c * 192 + 128];
      float wv = vp0[c * 64];
      float q0 = lopart(u0), q1 = lopart(u1), q2 = lopart(u2);
      float k0 = hipart(u0), k1 = hipart(u1), k2v = hipart(u2);
      float hh[10] = {ha.x, ha.y, ha.z, ha.w, hb.x, hb.y, hb.z, hb.w, hc.x, hc.y};
#pragma unroll
      for (int t = 0; t < 10; ++t) { float c_ = hh[t]; qr[t] += q1 * c_; kr[t] += k1 * c_; vr[t] += wv * c_; }
#pragma unroll
      for (int t = 1; t < 10; ++t) { float c_ = hh[t - 1]; qr[t] += q0 * c_; kr[t] += k0 * c_; }
#pragma unroll
      for (int t = 0; t < 9; ++t) { float c_ = hh[t + 1]; qr[t] += q2 * c_; kr[t] += k2v * c_; }
    }
  }
  __builtin_amdgcn_wave_barrier();
  // spill q and k as bf16 pairs (stride 5 u32 each)
  {
    u32* qu = (u32*)Aw + lane * 5;
    u32* ku = (u32*)Aw + 320 + lane * 5;
#pragma unroll
    for (int m = 0; m < 5; ++m) {
      qu[m] = cvtpk(qr[2 * m], qr[2 * m + 1]);
      ku[m] = cvtpk(kr[2 * m], kr[2 * m + 1]);
    }
  }
  __builtin_amdgcn_wave_barrier();

  // ---- scores + softmax: 80 (head,row) rows over 2 passes; P -> [640,1440)
  {
    const u32* qb = (const u32*)Aw;
    const u32* kb = (const u32*)Aw + 320;
#pragma unroll
    for (int pass = 0; pass < 2; ++pass) {
      int row = pass * 64 + lane;
      if (row < 80) {
        int h8 = (row / 10) * 8, r = row - (row / 10) * 10;
        int rm = r >> 1, rs = r & 1;
        float sv[10];
#pragma unroll
        for (int s = 0; s < 10; ++s) sv[s] = 0.f;
#pragma unroll 2
        for (int d = 0; d < 8; ++d) {
          int jj = h8 + d;
          u32 qu = qb[jj * 5 + rm];
          float qv = rs ? hipart(qu) : lopart(qu);
          const u32* kp2 = kb + jj * 5;
          u32 ka0 = kp2[0], ka1 = kp2[1], ka2 = kp2[2], ka3 = kp2[3], ka4 = kp2[4];
          sv[0] += qv * lopart(ka0); sv[1] += qv * hipart(ka0);
          sv[2] += qv * lopart(ka1); sv[3] += qv * hipart(ka1);
          sv[4] += qv * lopart(ka2); sv[5] += qv * hipart(ka2);
          sv[6] += qv * lopart(ka3); sv[7] += qv * hipart(ka3);
          sv[8] += qv * lopart(ka4); sv[9] += qv * hipart(ka4);
        }
        const float sc_ = 0.35355339059327373f;
        float mx = sv[0];
#pragma unroll
        for (int s = 1; s < 10; ++s) mx = fmaxf(mx, sv[s]);
        float tot = 0.f, ev[10];
#pragma unroll
        for (int s = 0; s < 10; ++s) { ev[s] = __expf((sv[s] - mx) * sc_); tot += ev[s]; }
        float inv = 1.f / tot;
        float* pp = Aw + 640 + row * 10;
#pragma unroll
        for (int s = 0; s < 10; ++s) pp[s] = ev[s] * inv;
      }
    }
  }
  __builtin_amdgcn_wave_barrier();

  // ---- PV: lane = j (head h=j>>3), v in regs, P broadcast per 8-lane group; o -> [0,768)
  {
    const float* pb = Aw + 640 + (lane >> 3) * 100;
    float orr[10];
#pragma unroll
    for (int t = 0; t < 10; ++t) {
      const float* pr = pb + t * 10;
      float a = 0.f;
#pragma unroll
      for (int s = 0; s < 10; ++s) a += pr[s] * vr[s];
      orr[t] = a;
    }
    float* op = Aw + lane * 12;
    *(float4*)op       = make_float4(orr[0], orr[1], orr[2], orr[3]);
    *(float4*)(op + 4) = make_float4(orr[4], orr[5], orr[6], orr[7]);
    *(float2*)(op + 8) = make_float2(orr[8], orr[9]);
  }
  __builtin_amdgcn_wave_barrier();

  // ---- fused lino+te2 + h3x store: lane = (c, th), 5 t's each
  {
    float bt2 = botp[cl];
    float a5[5];
#pragma unroll
    for (int k2 = 0; k2 < 5; ++k2) a5[k2] = bt2;
    const float* tp0 = otT + cl;
    const float* base = Aw + th * 5;
#pragma unroll 2
    for (int j = 0; j < 64; ++j) {
      float w = tp0[j * 32];
      const float* lp = base + j * 12;
#pragma unroll
      for (int k2 = 0; k2 < 5; ++k2) a5[k2] += w * lp[k2];
    }
    int t0 = th * 5;
#pragma unroll
    for (int k2 = 0; k2 < 5; ++k2)
      h3x[((b * 10 + t0 + k2) * 500 + n) * 32 + cl] = a5[k2];
  }
}

// ---------------- K2: MFMA z1 = A @ XT, z2 = A2 @ XT (round-12 form: grid (160,8)) ----------------
__global__ __launch_bounds__(256, 4) void k_z12m(const float* __restrict__ h3x,
    const u16* __restrict__ Abf, const u16* __restrict__ A2bf,
    float* __restrict__ z1x, float* __restrict__ z2x) {
  __shared__ u32 xlsT[8192];     // [n][half-row] pairs, swizzled (32 KB)
  int tid = threadIdx.x, bt = blockIdx.x;
  const float* src = h3x + bt * 16000;
  for (int i = tid; i < 8192; i += 256) {
    int n = i & 31, h = i >> 5;
    int r0 = 2 * h;
    float v0 = (r0 < 500) ? src[r0 * 32 + n] : 0.f;
    float v1 = (r0 + 1 < 500) ? src[(r0 + 1) * 32 + n] : 0.f;
    xlsT[n * 256 + (((h & 0xFC) ^ ((n & 15) << 2)) | (h & 3))] = cvtpk(v0, v1);
  }
  __syncthreads();
  int lane = tid & 63, wave = tid >> 6;
  int q = lane >> 4, ln = lane & 15;
  int rbase = blockIdx.y * 64 + wave * 16;
  const u32* Au = (const u32*)Abf;
  const u32* A2u = (const u32*)A2bf;
  int arow = (rbase + ln) * 256;
  union F8 { u32 u[4]; short8 s; };
  floatx4 acc1[2] = {{0.f,0.f,0.f,0.f},{0.f,0.f,0.f,0.f}};
  floatx4 acc2[2] = {{0.f,0.f,0.f,0.f},{0.f,0.f,0.f,0.f}};
  for (int c2 = 0; c2 < 16; ++c2) {
    int hb = c2 * 16 + q * 4;         // aligned half-row base for this quad's k-slice
    F8 a1f, a2f;
#pragma unroll
    for (int i2 = 0; i2 < 4; ++i2) {
      a1f.u[i2] = Au[arow + hb + i2];
      a2f.u[i2] = A2u[arow + hb + i2];
    }
#pragma unroll
    for (int t2 = 0; t2 < 2; ++t2) {
      int n = t2 * 16 + ln;
      int baseT = n * 256 + (hb ^ ((n & 15) << 2));
      F8 bf;
#pragma unroll
      for (int i2 = 0; i2 < 4; ++i2) bf.u[i2] = xlsT[baseT + i2];
      acc1[t2] = __builtin_amdgcn_mfma_f32_16x16x32_bf16(a1f.s, bf.s, acc1[t2], 0, 0, 0);
      acc2[t2] = __builtin_amdgcn_mfma_f32_16x16x32_bf16(a2f.s, bf.s, acc2[t2], 0, 0, 0);
    }
  }
  int outb = bt * 16000;
#pragma unroll
  for (int t2 = 0; t2 < 2; ++t2) {
#pragma unroll
    for (int i2 = 0; i2 < 4; ++i2) {
      int r = rbase + q * 4 + i2;
      if (r < 500) {
        z1x[outb + r * 32 + t2 * 16 + ln] = acc1[t2][i2];
        z2x[outb + r * 32 + t2 * 16 + ln] = acc2[t2][i2];
      }
    }
  }
}

// ---------------- K3: MFMA fused attention: out = softmax(K K^T / sqrt(32)) @ V ----------------
// STAGE-AMORTIZED: grid (160,2); each block stages K (stride-20, resident) AND V^T
// (z12m layout, resident) ONCE, then loops 8 row-chunks of 32 reusing the wave-pair
// schedule (acc[16]/wave, deferred normalization, per-wave pch). LDS 76.8 KB -> 2/CU;
// all 320 blocks co-resident (single generation).
__global__ __launch_bounds__(256, 2) void k_attn2(const float* __restrict__ keys,
                                                  const float* __restrict__ vals,
                                                  float* __restrict__ outp) {
  __shared__ u32 kls[10240];       // K rows stride-20 (40 KB), resident
  __shared__ u32 vls[8192];        // V^T z12m swizzled (32 KB), resident
  __shared__ u32 aux[1216];        // pch 4x272 @0 (reused as zex); smx @1088; sms @1152
  int tid = threadIdx.x, bt = blockIdx.x, yh = blockIdx.y;
  const float* kb = keys + bt * 16000;
  const float* vb = vals + bt * 16000;
  for (int i = tid; i < 8192; i += 256) {
    int r = i >> 4, cu = i & 15;
    float2 g = make_float2(0.f, 0.f);
    if (r < 500) g = *(const float2*)(kb + r * 32 + cu * 2);
    kls[r * 20 + cu] = cvtpk(g.x, g.y);
    int n = i & 31, h = i >> 5;
    int r0 = 2 * h;
    float v0 = (r0 < 500) ? vb[r0 * 32 + n] : 0.f;
    float v1 = (r0 + 1 < 500) ? vb[(r0 + 1) * 32 + n] : 0.f;
    vls[n * 256 + (((h & 0xFC) ^ ((n & 15) << 2)) | (h & 3))] = cvtpk(v0, v1);
  }
  __syncthreads();
  int lane = tid & 63, wave = tid >> 6;
  int q = lane >> 4, ln = lane & 15;
  int wrow = wave >> 1, ch = wave & 1;
  float* smx = (float*)(aux + 1088);
  float* sms = (float*)(aux + 1152);
  u32* myp = aux + wave * 272;
  float* zex = (float*)aux;
  u16* pw = (u16*)myp;
  union F8 { u32 u[4]; short8 s; };
  const float sc = 0.17677669529663687f;
  int outb = bt * 16000;
  for (int chunk = 0; chunk < 8; ++chunk) {
    int rbase = yh * 256 + chunk * 32 + wrow * 16;
    F8 af;
    {
      int r = rbase + ln;
      int wbase = r * 20 + q * 4;
#pragma unroll
      for (int i2 = 0; i2 < 4; ++i2)
        af.u[i2] = kls[wbase + i2];
    }
    floatx4 acc[16];
#pragma unroll
    for (int ctl = 0; ctl < 16; ++ctl) {
      int r2 = (ch * 16 + ctl) * 16 + ln;
      int wb2 = r2 * 20 + q * 4;
      F8 bf;
#pragma unroll
      for (int i2 = 0; i2 < 4; ++i2)
        bf.u[i2] = kls[wb2 + i2];
      acc[ctl] = __builtin_amdgcn_mfma_f32_16x16x32_bf16(af.s, bf.s,
                (floatx4){0.f, 0.f, 0.f, 0.f}, 0, 0, 0);
    }
    if (ch == 1 && ln >= 4) {
#pragma unroll
      for (int i2 = 0; i2 < 4; ++i2) acc[15][i2] = -1e30f;   // cols >= 500
    }
    float m[4];
#pragma unroll
    for (int i2 = 0; i2 < 4; ++i2) {
      float mm = -1e30f;
#pragma unroll
      for (int ctl = 0; ctl < 16; ++ctl) mm = fmaxf(mm, acc[ctl][i2]);
#pragma unroll
      for (int d = 1; d < 16; d <<= 1) mm = fmaxf(mm, __shfl_xor(mm, d));
      m[i2] = mm;
    }
    if (ln == 0) {
#pragma unroll
      for (int i2 = 0; i2 < 4; ++i2) smx[wave * 16 + q * 4 + i2] = m[i2];
    }
    __syncthreads();   // (A) smx visible; also orders prior chunk's zex reads
    float sp[4];
#pragma unroll
    for (int i2 = 0; i2 < 4; ++i2) {
      float mm = fmaxf(m[i2], smx[(wave ^ 1) * 16 + q * 4 + i2]);
      float s = 0.f;
#pragma unroll
      for (int ctl = 0; ctl < 16; ++ctl) {
        float e = __expf((acc[ctl][i2] - mm) * sc);
        acc[ctl][i2] = e; s += e;
      }
#pragma unroll
      for (int d = 1; d < 16; d <<= 1) s += __shfl_xor(s, d);
      sp[i2] = s;
    }
    if (ln == 0) {
#pragma unroll
      for (int i2 = 0; i2 < 4; ++i2) sms[wave * 16 + q * 4 + i2] = sp[i2];
    }
    __syncthreads();   // (B) sms visible
    float inv[4];
#pragma unroll
    for (int i2 = 0; i2 < 4; ++i2)
      inv[i2] = 1.f / (sp[i2] + sms[(wave ^ 1) * 16 + q * 4 + i2]);
    floatx4 zacc[2] = {{0.f,0.f,0.f,0.f},{0.f,0.f,0.f,0.f}};
    for (int c2l = 0; c2l < 8; ++c2l) {
#pragma unroll
      for (int t2 = 0; t2 < 2; ++t2) {
        int ctl = c2l * 2 + t2;
#pragma unroll
        for (int i2 = 0; i2 < 4; ++i2)
          pw[(q * 4 + i2) * 34 + t2 * 16 + ln] = f2b(acc[ctl][i2]);
      }
      __builtin_amdgcn_wave_barrier();
      F8 pa;
#pragma unroll
      for (int i2 = 0; i2 < 4; ++i2) pa.u[i2] = myp[ln * 17 + q * 4 + i2];
      int hb = (ch * 8 + c2l) * 16 + q * 4;     // this wave's half-k slice
#pragma unroll
      for (int t2 = 0; t2 < 2; ++t2) {
        int n = t2 * 16 + ln;
        int baseT = n * 256 + (hb ^ ((n & 15) << 2));
        F8 bf;
#pragma unroll
        for (int i2 = 0; i2 < 4; ++i2) bf.u[i2] = vls[baseT + i2];
        zacc[t2] = __builtin_amdgcn_mfma_f32_16x16x32_bf16(pa.s, bf.s, zacc[t2], 0, 0, 0);
      }
      __builtin_amdgcn_wave_barrier();
    }
    __syncthreads();   // (C1) all pch reads done before zex overwrite
    if (ch) {
#pragma unroll
      for (int t2 = 0; t2 < 2; ++t2)
#pragma unroll
        for (int i2 = 0; i2 < 4; ++i2)
          zex[wrow * 544 + (q * 4 + i2) * 34 + t2 * 16 + ln] = zacc[t2][i2];
    }
    __syncthreads();   // (C2) zex visible
    if (!ch) {
#pragma unroll
      for (int t2 = 0; t2 < 2; ++t2) {
#pragma unroll
        for (int i2 = 0; i2 < 4; ++i2) {
          int r = rbase + q * 4 + i2;
          if (r < 500) {
            float vsum = zacc[t2][i2] + zex[wrow * 544 + (q * 4 + i2) * 34 + t2 * 16 + ln];
            outp[outb + r * 32 + t2 * 16 + ln] = vsum * inv[i2];
          }
        }
      }
    }
  }
}

// ---------------- K4: MFMA mlp + gate + fused ct1 -> g2 ----------------
__global__ __launch_bounds__(256, 2) void k_gate(
    const float* __restrict__ h3x, const float* __restrict__ z1x, const float* __restrict__ z2x,
    const float* __restrict__ z3x, const float* __restrict__ z4x,
    const u32* __restrict__ WBq, const float* __restrict__ mlpB,
    const float* __restrict__ ct1W, const float* __restrict__ ct1B,
    float* __restrict__ g2w)
{
  __shared__ u32 wlds[5120];       // 20 KB: 20 B-frags x 64 lanes x 4 u32
  int tid = threadIdx.x;
  for (int i = tid; i < 5120; i += 256) wlds[i] = WBq[i];
  __syncthreads();
  int lane = tid & 63, wave = tid >> 6;
  int q = lane >> 4, ln = lane & 15;
  int b = blockIdx.y;
  int n0 = blockIdx.x * 32 + wave * 8;
  int nA = n0 + (ln & 7);          // A-row n for this lane
  int tAb = ln >> 3;               // A-row t_local (0/1)
  int nD = n0 + (q & 1) * 4;       // D-row n base (n = nD + i)
  int tDb = q >> 1;                // D-row t_local
  float g2a[4][2][6];
#pragma unroll
  for (int i = 0; i < 4; ++i)
#pragma unroll
    for (int ch = 0; ch < 2; ++ch)
#pragma unroll
      for (int s = 0; s < 6; ++s) g2a[i][ch][s] = 0.f;
  float bias[4];
#pragma unroll
  for (int ct = 0; ct < 4; ++ct) bias[ct] = mlpB[ct * 16 + ln];
  union F8 { u32 u[4]; short8 s; };
  for (int tile = 0; tile < 5; ++tile) {
    int tA = tile * 2 + tAb;
    int offA = (((b * 10 + tA) * 500) + nA) * 32 + q * 8;
    floatx4 acc[4];
#pragma unroll
    for (int ct = 0; ct < 4; ++ct) acc[ct] = (floatx4){bias[ct], bias[ct], bias[ct], bias[ct]};
#pragma unroll
    for (int kt = 0; kt < 5; ++kt) {
      const float* sp = kt == 0 ? h3x : kt == 1 ? z1x : kt == 2 ? z2x : kt == 3 ? z3x : z4x;
      float4 a0 = *(const float4*)(sp + offA);
      float4 a1 = *(const float4*)(sp + offA + 4);
      F8 af;
      af.u[0] = cvtpk(a0.x, a0.y);
      af.u[1] = cvtpk(a0.z, a0.w);
      af.u[2] = cvtpk(a1.x, a1.y);
      af.u[3] = cvtpk(a1.z, a1.w);
#pragma unroll
      for (int ct = 0; ct < 4; ++ct) {
        F8 bfr;
        const u32* wp = wlds + (((kt * 4 + ct) << 6) + lane) * 4;
#pragma unroll
        for (int i2 = 0; i2 < 4; ++i2) bfr.u[i2] = wp[i2];
        acc[ct] = __builtin_amdgcn_mfma_f32_16x16x32_bf16(af.s, bfr.s, acc[ct], 0, 0, 0);
      }
    }
    int tD = tile * 2 + tDb;
    float c6[6];
#pragma unroll
    for (int s = 0; s < 6; ++s) c6[s] = ct1W[s * 10 + tD];
#pragma unroll
    for (int i = 0; i < 4; ++i) {
      float e0 = __expf(2.f * acc[0][i]);
      float g0 = ((e0 - 1.f) / (e0 + 1.f)) * (1.f / (1.f + __expf(-acc[2][i])));
      float e1 = __expf(2.f * acc[1][i]);
      float g1 = ((e1 - 1.f) / (e1 + 1.f)) * (1.f / (1.f + __expf(-acc[3][i])));
#pragma unroll
      for (int s = 0; s < 6; ++s) {
        g2a[i][0][s] += g0 * c6[s];
        g2a[i][1][s] += g1 * c6[s];
      }
    }
  }
  // combine even-t (q=0,1) and odd-t (q=2,3) partial sums: lane pair = lane ^ 32
#pragma unroll
  for (int i = 0; i < 4; ++i)
#pragma unroll
    for (int ch = 0; ch < 2; ++ch)
#pragma unroll
      for (int s = 0; s < 6; ++s)
        g2a[i][ch][s] += __shfl_xor(g2a[i][ch][s], 32);
  if (q < 2) {
#pragma unroll
    for (int i = 0; i < 4; ++i) {
      int n = nD + i;
      if (n < 500) {
#pragma unroll
        for (int ch = 0; ch < 2; ++ch) {
          int c = ln + ch * 16;
          float* gp = g2w + ((b * 32 + c) * 500 + n) * 6;
#pragma unroll
          for (int s = 0; s < 6; ++s) gp[s] = g2a[i][ch][s] + ct1B[s];
        }
      }
    }
  }
}

// ---------------- K4b: fused f1 + f2 ----------------
__global__ __launch_bounds__(256) void k_f12(const float* __restrict__ g2w,
                                             const float* __restrict__ tc1W,
                                             const float* __restrict__ c2W,
                                             float* __restrict__ f1w, float* __restrict__ f2w) {
  int blk = blockIdx.x, tid = threadIdx.x;
  if (blk < 188) {
    int i = blk * 256 + tid;
    if (i >= 48000) return;
    int b = i / 3000, rem = i - b * 3000, s = rem / 500, n = rem - s * 500;
    float a = 0.f;
    for (int c = 0; c < 32; ++c) a += g2w[((b * 32 + c) * 500 + n) * 6 + s] * tc1W[c];
    f1w[(b * 6 + s) * 500 + n] = a;
  } else {
    int pb = (blk - 188) * 4 + (tid >> 6);   // 0..511 (b,c) pairs
    int b = pb >> 5, c = pb & 31, lane = tid & 63;
    float acc[6];
#pragma unroll
    for (int t = 0; t < 6; ++t) acc[t] = 0.f;
    for (int n = lane; n < 500; n += 64) {
      float w = c2W[n];
      const float* gp = g2w + ((b * 32 + c) * 500 + n) * 6;
#pragma unroll
      for (int t = 0; t < 6; ++t) acc[t] += w * gp[t];
    }
#pragma unroll
    for (int t = 0; t < 6; ++t)
      for (int off = 32; off; off >>= 1) acc[t] += __shfl_xor(acc[t], off);
    if (lane == 0) {
#pragma unroll
      for (int t = 0; t < 6; ++t) f2w[(b * 32 + c) * 6 + t] = acc[t];
    }
  }
}

// ---------------- K5b: per-b TATT ----------------
__global__ __launch_bounds__(256) void k_tatt(
    const float* __restrict__ f1w, const float* __restrict__ tatw,
    const float* __restrict__ f2w, const float* __restrict__ tatb, const float* __restrict__ tatv,
    float* __restrict__ lg2w)
{
  __shared__ float mid[192];
  __shared__ float lgt[36];
  int b = blockIdx.x, tid = threadIdx.x;
  if (tid < 192) {
    int t = tid >> 5, c = tid & 31;
    float a = 0.f;
    const float* f1p = f1w + (b * 6 + t) * 500;
    for (int n = 0; n < 500; ++n) a += f1p[n] * tatw[n * 32 + c];
    mid[t * 32 + c] = a;
  }
  __syncthreads();
  if (tid < 36) {
    int t = tid / 6, s = tid - t * 6;
    float a = tatb[t * 6 + s];
    for (int c = 0; c < 32; ++c) a += mid[t * 32 + c] * f2w[(b * 32 + c) * 6 + s];
    lgt[t * 6 + s] = 1.f / (1.f + expf(-a));
  }
  __syncthreads();
  if (tid < 36) {
    int p = tid / 6, s = tid - p * 6;
    float a = 0.f;
#pragma unroll
    for (int t2 = 0; t2 < 6; ++t2) a += tatv[p * 6 + t2] * lgt[t2 * 6 + s];
    lg2w[(b * 6 + p) * 6 + s] = a;
  }
}

// ---------------- K5c: BN1 + softmax -> Tc ----------------
__global__ __launch_bounds__(128) void k_coefs(const float* __restrict__ lg2w,
    const float* __restrict__ bn1g, const float* __restrict__ bn1b, float* __restrict__ tcw) {
  __shared__ float mu[6], iv[6], gg[6], bb[6];
  int tid = threadIdx.x;
  if (tid < 6) {
    float s = 0.f, sq = 0.f;
    for (int b = 0; b < 16; ++b)
      for (int q = 0; q < 6; ++q) {
        float v = lg2w[(b * 6 + q) * 6 + tid];
        s += v; sq += v * v;
      }
    float m = s / 96.f;
    mu[tid] = m;
    iv[tid] = rsqrtf(sq / 96.f - m * m + 1e-5f);
    gg[tid] = bn1g[tid]; bb[tid] = bn1b[tid];
  }
  __syncthreads();
  for (int idx = tid; idx < 96; idx += 128) {
    int b = idx / 6, q = idx - b * 6;
    float v[6], mx = -1e30f;
#pragma unroll
    for (int l = 0; l < 6; ++l) {
      v[l] = (lg2w[(b * 6 + q) * 6 + l] - mu[l]) * iv[l] * gg[l] + bb[l];
      mx = fmaxf(mx, v[l]);
    }
    float tot = 0.f;
#pragma unroll
    for (int l = 0; l < 6; ++l) { v[l] = expf(v[l] - mx); tot += v[l]; }
    float inv = 1.f / tot;
#pragma unroll
    for (int l = 0; l < 6; ++l) tcw[(b * 6 + l) * 6 + q] = v[l] * inv;
  }
}

// ---------------- K6a: xo = leaky(g2@Tc)+res6, per-c sum/sumsq ----------------
__global__ __launch_bounds__(256) void k_xo(const float* __restrict__ g2w,
    const float* __restrict__ res6, const float* __restrict__ tcw,
    float* __restrict__ xow, float* __restrict__ stats) {
  __shared__ float Tcl[36];
  __shared__ float redS[32][8], redQ[32][8];
  int b = blockIdx.x, chunk = blockIdx.y, tid = threadIdx.x;
  if (tid < 36) Tcl[tid] = tcw[b * 36 + tid];
  __syncthreads();
  int c = tid & 31, sub = tid >> 5;
  int n0 = chunk * 50;
  float s = 0.f, sq = 0.f;
  for (int idx = sub; idx < 300; idx += 8) {
    int nl = idx / 6, q = idx - nl * 6;
    int n = n0 + nl;
    int base = ((b * 32 + c) * 500 + n) * 6;
    const float* gp = g2w + base;
    float xv = 0.f;
#pragma unroll
    for (int l = 0; l < 6; ++l) xv += gp[l] * Tcl[l * 6 + q];
    xv = xv > 0.f ? xv : 0.01f * xv;
    xv += res6[base + q];
    xow[base + q] = xv;
    s += xv; sq += xv * xv;
  }
  redS[c][sub] = s; redQ[c][sub] = sq;
  __syncthreads();
  if (sub == 0) {
    float ts = 0.f, tq = 0.f;
#pragma unroll
    for (int k = 0; k < 8; ++k) { ts += redS[c][k]; tq += redQ[c][k]; }
    atomicAdd(&stats[c], ts);
    atomicAdd(&stats[32 + c], tq);
  }
}

// ---------------- K6b: BN2 normalize -> FP32 out ----------------
__global__ __launch_bounds__(256) void k_out(const float* __restrict__ xow,
    const float* __restrict__ stats, const float* __restrict__ g2c, const float* __restrict__ b2c,
    float* __restrict__ out) {
  int base = (blockIdx.x * 256 + threadIdx.x) * 4;
#pragma unroll
  for (int k = 0; k < 4; ++k) {
    int i = base + k;
    int c = (i / 3000) & 31;
    float m = stats[c] * (1.f / 48000.f);
    float var = stats[32 + c] * (1.f / 48000.f) - m * m;
    out[i] = (xow[i] - m) * rsqrtf(var + 1e-5f) * g2c[c] + b2c[c];
  }
}

extern "C" void kernel_launch(void* const* d_in, const int* in_sizes, int n_in,
                              void* d_out, int out_size, void* d_ws, size_t ws_size,
                              hipStream_t stream)
{
  (void)in_sizes; (void)out_size;

  float* ws = (float*)d_ws;
  float* Af   = ws;                 // 250,000 (unused; layout kept)
  float* Wf   = Af + 250000;        // 65,536 (65,322 used)
  float* A2   = Wf + 65536;         // 250,000 (unused; layout kept)
  float* h3x  = A2 + 250000;        // 2,560,000 (B,T,N,32)
  float* z1x  = h3x + 2560000;
  float* z2x  = z1x + 2560000;
  float* z3x  = z2x + 2560000;
  float* z4x  = z3x + 2560000;
  float* res6 = z4x + 2560000;      // 1,536,000
  float* g2w  = res6 + 1536000;     // 1,536,000
  float* f1w  = g2w + 1536000;      // 48,000
  float* f2w  = f1w + 48000;        // 3,072
  float* lg2w = f2w + 3072;         // 576
  float* tcw  = lg2w + 576;         // 576
  float* stats= tcw + 576;          // 64
  float* xow  = z1x;                // reuse z1 region after k_gate
  u16*   Abf  = (u16*)g2w;          // 512x512 bf16 A pack (g2w region dead until k_gate)
  u16*   A2bf = (u16*)(g2w + 131072); // 512x512 bf16 A2 pack
  float* WTp  = g2w + 262144;       // 11,744 folded-weight pack (dead before k_gate)
  u16*   WBu  = (u16*)f1w;          // 10,240 u16 mlpW B-frag pack (f1w region dead until k_f12)
  if (ws_size < (size_t)16489952 * sizeof(float)) return;  // workspace guard

  // converted-weight offsets inside Wf (cumulative over dict inputs 2..28)
  const float* c1B  = Wf + 1024;
  const float* mlpB = Wf + 48512;
  const float* ct1W = Wf + 48576;
  const float* ct1B = Wf + 48636;
  const float* tc1W = Wf + 48642;
  const float* tc2W = Wf + 48674;
  const float* tatw = Wf + 49174;
  const float* tatb = Wf + 65174;
  const float* tatv = Wf + 65210;
  const float* bn1g = Wf + 65246;
  const float* bn1b = Wf + 65252;
  const float* bn2g = Wf + 65258;
  const float* bn2b = Wf + 65290;

  Ptrs ps;
  for (int i = 0; i < 29; ++i) ps.p[i] = (i < n_in) ? d_in[i] : d_in[0];

  k_prep <<<dim3(1367),    256, 0, stream>>>(ps, Wf, Abf, WTp, WBu, stats);
  k_a2m  <<<dim3(16, 8),   256, 0, stream>>>(Abf, A2bf);
  k_front3<<<dim3(2000),   256, 0, stream>>>(ps.p[0], ps.p[25], WTp, c1B, h3x, res6);
  k_z12m <<<dim3(160, 8),  256, 0, stream>>>(h3x, Abf, A2bf, z1x, z2x);
  k_attn2<<<dim3(160, 2),  256, 0, stream>>>(h3x, h3x, z3x);
  k_attn2<<<dim3(160, 2),  256, 0, stream>>>(h3x, z3x, z4x);
  k_gate <<<dim3(16, 16),  256, 0, stream>>>(h3x, z1x, z2x, z3x, z4x,
                                             (const u32*)WBu, mlpB, ct1W, ct1B, g2w);
  k_f12  <<<dim3(316),     256, 0, stream>>>(g2w, tc1W, tc2W, f1w, f2w);
  k_tatt <<<dim3(16),      256, 0, stream>>>(f1w, tatw, f2w, tatb, tatv, lg2w);
  k_coefs<<<dim3(1),       128, 0, stream>>>(lg2w, bn1g, bn1b, tcw);
  k_xo   <<<dim3(16, 10),  256, 0, stream>>>(g2w, res6, tcw, xow, stats);
  k_out  <<<dim3(1500),    256, 0, stream>>>(xow, stats, bn2g, bn2b, (float*)d_out);
}

// Round 15
// 391.905 us; speedup vs baseline: 1.0633x; 1.0234x over previous
//
#include <hip/hip_runtime.h>

typedef unsigned short u16;
typedef unsigned int u32;

__device__ __forceinline__ float b2f(u16 v) { return __uint_as_float((u32)v << 16); }
__device__ __forceinline__ float lopart(u32 u) { return __uint_as_float(u << 16); }
__device__ __forceinline__ float hipart(u32 u) { return __uint_as_float(u & 0xffff0000u); }
__device__ __forceinline__ u16 f2b(float f) {
  u32 u = __float_as_uint(f);
  u32 r = u + 0x7fffu + ((u >> 16) & 1u);
  return (u16)(r >> 16);
}
__device__ __forceinline__ u32 pk2(float a, float b) {
  return (u32)f2b(a) | ((u32)f2b(b) << 16);
}
__device__ __forceinline__ u32 cvtpk(float lo, float hi) {
  u32 r;
  asm("v_cvt_pk_bf16_f32 %0, %1, %2" : "=v"(r) : "v"(lo), "v"(hi));
  return r;
}
__device__ __forceinline__ float rd(const void* p, int i, bool BF) {
  return BF ? b2f(((const u16*)p)[i]) : ((const float*)p)[i];
}

struct Ptrs { const void* p[29]; };

typedef __attribute__((ext_vector_type(8))) short short8;
typedef __attribute__((ext_vector_type(4))) float floatx4;

// ---------------- K-prep: fused cvt + A-pack + folded-weight prep + MFMA frag packs + stats ----
// WT layout (float idx unless noted):
//   c1T  [0,1024)        : [i*32+c] = c1W[c*32+i]
//   bv   [9600,9664)     : lvB[o] + sum_i lvW[o,i]*te1B[i]
//   otT  [9664,11712)    : [j*32+c] = sum_o te2W[c,o]*loW[o,j]
//   bot  [11712,11744)   : te2B[c] + sum_o te2W[c,o]*loB[o]
//   (u32) WQKf [22016,28160): A-frags for [q;k][128x96] fold, [ks][mt(8)][lane][i2]
//   (u32) WVf  [28160,29184): A-frags for v[64x32] fold, [mt(4)][lane][i2]
//   bq3 [29184,29568), bk3 [29568,29952): per-t-class biases [cls(3)][o]
// WBu: mlpW bf16 B-frag pack (unchanged)
__global__ __launch_bounds__(256) void k_prep(Ptrs ps, float* __restrict__ Wf,
                                              u16* __restrict__ Abf, float* __restrict__ WT,
                                              u16* __restrict__ WBu, float* __restrict__ stats) {
  bool BF = ((*(const u32*)ps.p[25]) & 0xffffu) != 0;
  int blk = blockIdx.x, tid = threadIdx.x;
  const void* p2  = ps.p[2];
  const void* p4  = ps.p[4];
  const void* p5  = ps.p[5];
  const void* p6  = ps.p[6];
  const void* p7  = ps.p[7];
  const void* p8  = ps.p[8];
  const void* p9  = ps.p[9];
  const void* p10 = ps.p[10];
  const void* p11 = ps.p[11];
  const void* p12 = ps.p[12];
  const void* p13 = ps.p[13];
  const void* p14 = ps.p[14];
  const void* p15 = ps.p[15];
  const void* p16 = ps.p[16];
  if (blk < 256) {
    int j = blk * 256 + tid;
    if (j >= 65322) return;
    const int SZ[27] = {1024,32,2048,64,12288,64,12288,64,4096,64,4096,64,2048,32,
                        10240,64,60,6,32,500,16000,36,36,6,6,32,32};
    int t = 0, off = 0;
#pragma unroll
    for (int k = 0; k < 27; ++k) {
      if (t == k && j >= off + SZ[k]) { off += SZ[k]; t = k + 1; }
    }
    Wf[j] = rd(ps.p[2 + t], j - off, BF);
  } else if (blk < 1280) {
    int i = (blk - 256) * 256 + tid;
    int r = i >> 9, v = i & 511;
    bool in = (r < 500) && (v < 500);
    u16 o = 0;
    if (in) o = BF ? ((const u16*)ps.p[1])[r * 500 + v] : f2b(((const float*)ps.p[1])[r * 500 + v]);
    Abf[i] = o;
  } else if (blk < 1366) {
    int i = (blk - 1280) * 256 + tid;
    if (i < 1024) {
      WT[i] = rd(p2, (i & 31) * 32 + (i >> 5), BF);
    } else if (i >= 9600 && i < 9664) {
      int o = i - 9600;
      float s = rd(p11, o, BF);
      for (int i2 = 0; i2 < 64; ++i2)
        s += rd(p10, o * 64 + i2, BF) * rd(p5, i2, BF);
      WT[i] = s;
    } else if (i >= 9664 && i < 11712) {
      int j2 = i - 9664;
      int jj = j2 >> 5, c = j2 & 31;
      float s = 0.f;
      for (int o2 = 0; o2 < 64; ++o2)
        s += rd(p14, c * 64 + o2, BF) * rd(p12, o2 * 64 + jj, BF);
      WT[i] = s;
    } else if (i >= 11712 && i < 11744) {
      int c = i - 11712;
      float s = rd(p15, c, BF);
      for (int o2 = 0; o2 < 64; ++o2)
        s += rd(p14, c * 64 + o2, BF) * rd(p13, o2, BF);
      WT[i] = s;
    } else if (i >= 11744 && i < 21984) {
      int j2 = i - 11744;
      int j = j2 & 7, lanev = (j2 >> 3) & 63, ct = (j2 >> 9) & 3, kt = j2 >> 11;
      int qv = lanev >> 4, lnv = lanev & 15;
      int o = ct * 16 + lnv, k = kt * 32 + qv * 8 + j;
      WBu[j2] = f2b(rd(p16, o * 160 + k, BF));
    }
  } else if (blk < 1390) {
    // WQK A-frags: tile mt (0-3 q rows, 4-7 k rows), K-step ks (= tap), 16x32 each
    int idx = (blk - 1366) * 256 + tid;   // < 6144
    int i2 = idx & 3, lanev = (idx >> 2) & 63, mt = (idx >> 8) & 7, ks = idx >> 11;
    int q2 = lanev >> 4, ln = lanev & 15;
    int o = (mt & 3) * 16 + ln;
    const void* src = (mt >= 4) ? p8 : p6;
    int kb0 = q2 * 8 + 2 * i2;
    float v0 = 0.f, v1 = 0.f;
    for (int i3 = 0; i3 < 64; ++i3) {
      float w = rd(src, o * 192 + i3 * 3 + ks, BF);
      v0 += w * rd(p4, i3 * 32 + kb0, BF);
      v1 += w * rd(p4, i3 * 32 + kb0 + 1, BF);
    }
    ((u32*)WT)[22016 + idx] = pk2(v0, v1);
  } else if (blk < 1394) {
    // WV A-frags: 4 tiles of v[64x32] fold
    int idx = (blk - 1390) * 256 + tid;   // < 1024
    int i2 = idx & 3, lanev = (idx >> 2) & 63, mt = idx >> 8;
    int o = mt * 16 + (lanev & 15);
    int kb0 = (lanev >> 4) * 8 + 2 * i2;
    float v0 = 0.f, v1 = 0.f;
    for (int i3 = 0; i3 < 64; ++i3) {
      float w = rd(p10, o * 64 + i3, BF);
      v0 += w * rd(p4, i3 * 32 + kb0, BF);
      v1 += w * rd(p4, i3 * 32 + kb0 + 1, BF);
    }
    ((u32*)WT)[28160 + idx] = pk2(v0, v1);
  } else if (blk < 1397) {
    // per-t-class bias tables: cls 0 (t==0): b+S1+S2; 1 (mid): b+S0+S1+S2; 2 (t==9): b+S0+S1
    int j = (blk - 1394) * 256 + tid;     // < 768
    if (j < 768) {
      bool isK = j >= 384;
      int jj = isK ? j - 384 : j;
      int cls = jj >> 6, o = jj & 63;
      const void* srcW = isK ? p8 : p6;
      const void* srcB = isK ? p9 : p7;
      float S0 = 0.f, S1 = 0.f, S2 = 0.f;
      for (int i3 = 0; i3 < 64; ++i3) {
        float tb = rd(p5, i3, BF);
        S0 += rd(srcW, o * 192 + i3 * 3 + 0, BF) * tb;
        S1 += rd(srcW, o * 192 + i3 * 3 + 1, BF) * tb;
        S2 += rd(srcW, o * 192 + i3 * 3 + 2, BF) * tb;
      }
      float val = rd(srcB, o, BF) + S1 + (cls > 0 ? S0 : 0.f) + (cls < 2 ? S2 : 0.f);
      WT[29184 + j] = val;
    }
  } else {
    if (tid < 64) stats[tid] = 0.f;
  }
}

// ---------------- K0m: MFMA A2 = A @ A (bf16 in/out, fp32 accumulate) ----------------
__global__ __launch_bounds__(256, 4) void k_a2m(const u16* __restrict__ Abf,
                                                u16* __restrict__ A2bf) {
  __shared__ u32 blsT[8192];     // [c][k-pair] swizzled (32 KB), c = local col
  int tid = threadIdx.x;
  int c0 = blockIdx.x * 32;
  for (int i = tid; i < 8192; i += 256) {
    int c = i & 31, h = i >> 5;
    int r0 = 2 * h;
    u32 lo = Abf[r0 * 512 + c0 + c];
    u32 hi = Abf[(r0 + 1) * 512 + c0 + c];
    blsT[c * 256 + (((h & 0xFC) ^ ((c & 15) << 2)) | (h & 3))] = lo | (hi << 16);
  }
  __syncthreads();
  int lane = tid & 63, wave = tid >> 6;
  int q = lane >> 4, ln = lane & 15;
  int rbase = blockIdx.y * 64 + wave * 16;
  const u32* Au = (const u32*)Abf;
  int arow = (rbase + ln) * 256;
  union F8 { u32 u[4]; short8 s; };
  floatx4 acc[2] = {{0.f,0.f,0.f,0.f},{0.f,0.f,0.f,0.f}};
  for (int c2 = 0; c2 < 16; ++c2) {
    int hb = c2 * 16 + q * 4;
    F8 af;
#pragma unroll
    for (int i2 = 0; i2 < 4; ++i2) af.u[i2] = Au[arow + hb + i2];
#pragma unroll
    for (int t2 = 0; t2 < 2; ++t2) {
      int c = t2 * 16 + ln;
      int baseT = c * 256 + (hb ^ ((c & 15) << 2));
      F8 bf;
#pragma unroll
      for (int i2 = 0; i2 < 4; ++i2) bf.u[i2] = blsT[baseT + i2];
      acc[t2] = __builtin_amdgcn_mfma_f32_16x16x32_bf16(af.s, bf.s, acc[t2], 0, 0, 0);
    }
  }
#pragma unroll
  for (int t2 = 0; t2 < 2; ++t2) {
#pragma unroll
    for (int i2 = 0; i2 < 4; ++i2) {
      int r = rbase + q * 4 + i2;
      A2bf[r * 512 + c0 + t2 * 16 + ln] = f2b(acc[t2][i2]);
    }
  }
}

// ---------------- K1: frontend, qkv via MFMA; one (b,n) pair per WAVE, zero block barriers --------
// Per-wave LDS arena 1680 floats (26.9 KB/block -> 5+ blocks/CU):
//   x f32 [0,384)  (dead after xT3 build + residual)
//   xT3 bf16 [384,1216) u32: [t(16)][96 k, stride 52 u32] = xpad[c][t-1+tau] (3-tap B matrix)
//   q bf16 [0,320) u32 / k bf16 [320,640) u32 (spilled post-MFMA; x/xT3 prefix dead)
//   v bf16 [960,1280) u32 ; P bf16 [1280,1680) u32 ; o f32 [0,768) (post-scores)
__global__ __launch_bounds__(256, 5) void k_front3(
    const void* __restrict__ xraw, const void* __restrict__ g1, const float* __restrict__ WT,
    const float* __restrict__ c1B,
    float* __restrict__ h3x, float* __restrict__ res6)
{
  __shared__ __align__(16) float arena[4][1680];
  int tid = threadIdx.x;
  int wave = tid >> 6, lane = tid & 63;
  float* Aw = arena[wave];
  int pair = blockIdx.x * 4 + wave;
  int b = pair / 500, n = pair - b * 500;

  const float* c1T  = WT;
  const float* bvp  = WT + 9600;
  const float* otT  = WT + 9664;
  const float* botp = WT + 11712;
  const u32* WQKf = (const u32*)WT + 22016;
  const u32* WVf  = (const u32*)WT + 28160;
  const float* bq3 = WT + 29184;
  const float* bk3 = WT + 29568;

  // ---- x -> LDS rows [c*12 + t] (convert at point of use)
  {
    bool BF = ((*(const u32*)g1) & 0xffffu) != 0;
    int c0 = lane >> 1, hf = (lane & 1) * 5;
    int base = ((b * 32 + c0) * 500 + n) * 10 + hf;
    float* dst = Aw + c0 * 12 + hf;
    if (BF) {
      const u16* xp = (const u16*)xraw + base;
#pragma unroll
      for (int k2 = 0; k2 < 5; ++k2) dst[k2] = b2f(xp[k2]);
    } else {
      const float* xp = (const float*)xraw + base;
#pragma unroll
      for (int k2 = 0; k2 < 5; ++k2) dst[k2] = xp[k2];
    }
  }
  __builtin_amdgcn_wave_barrier();

  int cl = lane & 31, th = lane >> 5;
  int q2 = lane >> 4, ln15 = lane & 15;

  // ---- residual: lane=(c, th), 3 time outputs each
  {
    float r0 = c1B[cl], r1 = r0, r2 = r0;
#pragma unroll 4
    for (int i = 0; i < 32; ++i) {
      float w = c1T[i * 32 + cl];
      const float* xr = Aw + i * 12 + 4 + th * 3;
      r0 += w * xr[0]; r1 += w * xr[1]; r2 += w * xr[2];
    }
    float* rp = res6 + ((b * 32 + cl) * 500 + n) * 6 + th * 3;
    rp[0] = r0; rp[1] = r1; rp[2] = r2;
  }

  // ---- build xT3 (B matrix, bf16): row t, col k = tau*32+c -> xpad[c][t-1+tau]
  {
    u32* xT3u = (u32*)Aw + 384;
    for (int e = lane; e < 480; e += 64) {
      int t = e / 48, col2 = e - t * 48;
      int kk0 = col2 * 2, kk1 = kk0 + 1;
      int tau0 = kk0 >> 5, c0 = kk0 & 31;
      int tau1 = kk1 >> 5, c1 = kk1 & 31;
      int tx0 = t - 1 + tau0, tx1 = t - 1 + tau1;
      float f0 = (tx0 >= 0 && tx0 < 10) ? Aw[c0 * 12 + tx0] : 0.f;
      float f1 = (tx1 >= 0 && tx1 < 10) ? Aw[c1 * 12 + tx1] : 0.f;
      xT3u[t * 52 + col2] = cvtpk(f0, f1);
    }
  }
  __builtin_amdgcn_wave_barrier();

  // ---- qkv via MFMA: [q;k] = Wqk[128x96] @ xpad ; v = Wv[64x32] @ x (ks=1 slice)
  union F8 { u32 u[4]; short8 s; };
  floatx4 aq[4] = {{0.f,0.f,0.f,0.f},{0.f,0.f,0.f,0.f},{0.f,0.f,0.f,0.f},{0.f,0.f,0.f,0.f}};
  floatx4 ak[4] = {{0.f,0.f,0.f,0.f},{0.f,0.f,0.f,0.f},{0.f,0.f,0.f,0.f},{0.f,0.f,0.f,0.f}};
  floatx4 av[4] = {{0.f,0.f,0.f,0.f},{0.f,0.f,0.f,0.f},{0.f,0.f,0.f,0.f},{0.f,0.f,0.f,0.f}};
  {
    const u32* xT3u = (const u32*)Aw + 384;
#pragma unroll
    for (int ks = 0; ks < 3; ++ks) {
      F8 bfr;
      const u32* bp = xT3u + ln15 * 52 + ks * 16 + q2 * 4;
#pragma unroll
      for (int i2 = 0; i2 < 4; ++i2) bfr.u[i2] = bp[i2];
#pragma unroll
      for (int mt = 0; mt < 4; ++mt) {
        F8 afr;
        const u32* ap = WQKf + ((ks * 8 + mt) * 64 + lane) * 4;
#pragma unroll
        for (int i2 = 0; i2 < 4; ++i2) afr.u[i2] = ap[i2];
        aq[mt] = __builtin_amdgcn_mfma_f32_16x16x32_bf16(afr.s, bfr.s, aq[mt], 0, 0, 0);
      }
#pragma unroll
      for (int mt = 0; mt < 4; ++mt) {
        F8 afr;
        const u32* ap = WQKf + ((ks * 8 + 4 + mt) * 64 + lane) * 4;
#pragma unroll
        for (int i2 = 0; i2 < 4; ++i2) afr.u[i2] = ap[i2];
        ak[mt] = __builtin_amdgcn_mfma_f32_16x16x32_bf16(afr.s, bfr.s, ak[mt], 0, 0, 0);
      }
      if (ks == 1) {
#pragma unroll
        for (int mt = 0; mt < 4; ++mt) {
          F8 afr;
          const u32* ap = WVf + (mt * 64 + lane) * 4;
#pragma unroll
          for (int i2 = 0; i2 < 4; ++i2) afr.u[i2] = ap[i2];
          av[mt] = __builtin_amdgcn_mfma_f32_16x16x32_bf16(afr.s, bfr.s, av[mt], 0, 0, 0);
        }
      }
    }
  }
  __builtin_amdgcn_wave_barrier();
  // ---- bias + spill q,k,v bf16 in [o][t] layout (cols t>=10 discarded)
  if (ln15 < 10) {
    int t = ln15;
    int cls = (t == 0) ? 0 : ((t == 9) ? 2 : 1);
    const float* bq = bq3 + cls * 64;
    const float* bk = bk3 + cls * 64;
    u16* q16 = (u16*)Aw;
    u16* k16 = (u16*)((u32*)Aw + 320);
    u16* v16 = (u16*)((u32*)Aw + 960);
#pragma unroll
    for (int mt = 0; mt < 4; ++mt) {
#pragma unroll
      for (int i2 = 0; i2 < 4; ++i2) {
        int o = mt * 16 + q2 * 4 + i2;
        q16[o * 10 + t] = f2b(aq[mt][i2] + bq[o]);
        k16[o * 10 + t] = f2b(ak[mt][i2] + bk[o]);
        v16[o * 10 + t] = f2b(av[mt][i2] + bvp[o]);
      }
    }
  }
  __builtin_amdgcn_wave_barrier();

  // ---- scores + softmax: 80 (head,row) rows over 2 passes; P bf16 -> [1280,1680)
  {
    const u32* qb = (const u32*)Aw;
    const u32* kb = (const u32*)Aw + 320;
#pragma unroll
    for (int pass = 0; pass < 2; ++pass) {
      int row = pass * 64 + lane;
      if (row < 80) {
        int h8 = (row / 10) * 8, r = row - (row / 10) * 10;
        int rm = r >> 1, rs = r & 1;
        float sv[10];
#pragma unroll
        for (int s = 0; s < 10; ++s) sv[s] = 0.f;
#pragma unroll 2
        for (int d = 0; d < 8; ++d) {
          int jj = h8 + d;
          u32 qu = qb[jj * 5 + rm];
          float qv = rs ? hipart(qu) : lopart(qu);
          const u32* kp2 = kb + jj * 5;
          u32 ka0 = kp2[0], ka1 = kp2[1], ka2 = kp2[2], ka3 = kp2[3], ka4 = kp2[4];
          sv[0] += qv * lopart(ka0); sv[1] += qv * hipart(ka0);
          sv[2] += qv * lopart(ka1); sv[3] += qv * hipart(ka1);
          sv[4] += qv * lopart(ka2); sv[5] += qv * hipart(ka2);
          sv[6] += qv * lopart(ka3); sv[7] += qv * hipart(ka3);
          sv[8] += qv * lopart(ka4); sv[9] += qv * hipart(ka4);
        }
        const float sc_ = 0.35355339059327373f;
        float mx = sv[0];
#pragma unroll
        for (int s = 1; s < 10; ++s) mx = fmaxf(mx, sv[s]);
        float tot = 0.f, ev[10];
#pragma unroll
        for (int s = 0; s < 10; ++s) { ev[s] = __expf((sv[s] - mx) * sc_); tot += ev[s]; }
        float inv = 1.f / tot;
        u32* pp = (u32*)Aw + 1280 + row * 5;
#pragma unroll
        for (int m2 = 0; m2 < 5; ++m2)
          pp[m2] = cvtpk(ev[2 * m2] * inv, ev[2 * m2 + 1] * inv);
      }
    }
  }
  __builtin_amdgcn_wave_barrier();

  // ---- PV: lane = j (head h=j>>3), v from LDS bf16, P bf16 broadcast; o -> [0,768) f32
  {
    float vrL[10];
    const u32* vp = (const u32*)Aw + 960 + lane * 5;
#pragma unroll
    for (int m2 = 0; m2 < 5; ++m2) {
      u32 w = vp[m2];
      vrL[2 * m2] = lopart(w); vrL[2 * m2 + 1] = hipart(w);
    }
    const u32* pb = (const u32*)Aw + 1280 + (lane >> 3) * 50;
    float orr[10];
#pragma unroll
    for (int t = 0; t < 10; ++t) {
      const u32* pr = pb + t * 5;
      float a = 0.f;
#pragma unroll
      for (int m2 = 0; m2 < 5; ++m2) {
        u32 w = pr[m2];
        a += lopart(w) * vrL[2 * m2] + hipart(w) * vrL[2 * m2 + 1];
      }
      orr[t] = a;
    }
    float* op = Aw + lane * 12;
    *(float4*)op       = make_float4(orr[0], orr[1], orr[2], orr[3]);
    *(float4*)(op + 4) = make_float4(orr[4], orr[5], orr[6], orr[7]);
    *(float2*)(op + 8) = make_float2(orr[8], orr[9]);
  }
  __builtin_amdgcn_wave_barrier();

  // ---- fused lino+te2 + h3x store: lane = (c, th), 5 t's each
  {
    float bt2 = botp[cl];
    float a5[5];
#pragma unroll
    for (int k2 = 0; k2 < 5; ++k2) a5[k2] = bt2;
    const float* tp0 = otT + cl;
    const float* base = Aw + th * 5;
#pragma unroll 2
    for (int j = 0; j < 64; ++j) {
      float w = tp0[j * 32];
      const float* lp = base + j * 12;
#pragma unroll
      for (int k2 = 0; k2 < 5; ++k2) a5[k2] += w * lp[k2];
    }
    int t0 = th * 5;
#pragma unroll
    for (int k2 = 0; k2 < 5; ++k2)
      h3x[((b * 10 + t0 + k2) * 500 + n) * 32 + cl] = a5[k2];
  }
}

// ---------------- K2: MFMA z1 = A @ XT, z2 = A2 @ XT ----------------
__global__ __launch_bounds__(256, 4) void k_z12m(const float* __restrict__ h3x,
    const u16* __restrict__ Abf, const u16* __restrict__ A2bf,
    float* __restrict__ z1x, float* __restrict__ z2x) {
  __shared__ u32 xlsT[8192];     // [n][half-row] pairs, swizzled (32 KB)
  int tid = threadIdx.x, bt = blockIdx.x;
  const float* src = h3x + bt * 16000;
  for (int i = tid; i < 8192; i += 256) {
    int n = i & 31, h = i >> 5;
    int r0 = 2 * h;
    float v0 = (r0 < 500) ? src[r0 * 32 + n] : 0.f;
    float v1 = (r0 + 1 < 500) ? src[(r0 + 1) * 32 + n] : 0.f;
    xlsT[n * 256 + (((h & 0xFC) ^ ((n & 15) << 2)) | (h & 3))] = cvtpk(v0, v1);
  }
  __syncthreads();
  int lane = tid & 63, wave = tid >> 6;
  int q = lane >> 4, ln = lane & 15;
  int rbase = blockIdx.y * 64 + wave * 16;
  const u32* Au = (const u32*)Abf;
  const u32* A2u = (const u32*)A2bf;
  int arow = (rbase + ln) * 256;
  union F8 { u32 u[4]; short8 s; };
  floatx4 acc1[2] = {{0.f,0.f,0.f,0.f},{0.f,0.f,0.f,0.f}};
  floatx4 acc2[2] = {{0.f,0.f,0.f,0.f},{0.f,0.f,0.f,0.f}};
  for (int c2 = 0; c2 < 16; ++c2) {
    int hb = c2 * 16 + q * 4;         // aligned half-row base for this quad's k-slice
    F8 a1f, a2f;
#pragma unroll
    for (int i2 = 0; i2 < 4; ++i2) {
      a1f.u[i2] = Au[arow + hb + i2];
      a2f.u[i2] = A2u[arow + hb + i2];
    }
#pragma unroll
    for (int t2 = 0; t2 < 2; ++t2) {
      int n = t2 * 16 + ln;
      int baseT = n * 256 + (hb ^ ((n & 15) << 2));
      F8 bf;
#pragma unroll
      for (int i2 = 0; i2 < 4; ++i2) bf.u[i2] = xlsT[baseT + i2];
      acc1[t2] = __builtin_amdgcn_mfma_f32_16x16x32_bf16(a1f.s, bf.s, acc1[t2], 0, 0, 0);
      acc2[t2] = __builtin_amdgcn_mfma_f32_16x16x32_bf16(a2f.s, bf.s, acc2[t2], 0, 0, 0);
    }
  }
  int outb = bt * 16000;
#pragma unroll
  for (int t2 = 0; t2 < 2; ++t2) {
#pragma unroll
    for (int i2 = 0; i2 < 4; ++i2) {
      int r = rbase + q * 4 + i2;
      if (r < 500) {
        z1x[outb + r * 32 + t2 * 16 + ln] = acc1[t2][i2];
        z2x[outb + r * 32 + t2 * 16 + ln] = acc2[t2][i2];
      }
    }
  }
}

// ---------------- K3: MFMA fused attention: out = softmax(K K^T / sqrt(32)) @ V ----------------
// STAGE-AMORTIZED: grid (160,2); K (stride-20) and V^T (z12m layout) both resident;
// 8 row-chunks of 32 with wave-pair schedule (acc[16]/wave, deferred normalization).
__global__ __launch_bounds__(256, 2) void k_attn2(const float* __restrict__ keys,
                                                  const float* __restrict__ vals,
                                                  float* __restrict__ outp) {
  __shared__ u32 kls[10240];       // K rows stride-20 (40 KB), resident
  __shared__ u32 vls[8192];        // V^T z12m swizzled (32 KB), resident
  __shared__ u32 aux[1216];        // pch 4x272 @0 (reused as zex); smx @1088; sms @1152
  int tid = threadIdx.x, bt = blockIdx.x, yh = blockIdx.y;
  const float* kb = keys + bt * 16000;
  const float* vb = vals + bt * 16000;
  for (int i = tid; i < 8192; i += 256) {
    int r = i >> 4, cu = i & 15;
    float2 g = make_float2(0.f, 0.f);
    if (r < 500) g = *(const float2*)(kb + r * 32 + cu * 2);
    kls[r * 20 + cu] = cvtpk(g.x, g.y);
    int n = i & 31, h = i >> 5;
    int r0 = 2 * h;
    float v0 = (r0 < 500) ? vb[r0 * 32 + n] : 0.f;
    float v1 = (r0 + 1 < 500) ? vb[(r0 + 1) * 32 + n] : 0.f;
    vls[n * 256 + (((h & 0xFC) ^ ((n & 15) << 2)) | (h & 3))] = cvtpk(v0, v1);
  }
  __syncthreads();
  int lane = tid & 63, wave = tid >> 6;
  int q = lane >> 4, ln = lane & 15;
  int wrow = wave >> 1, ch = wave & 1;
  float* smx = (float*)(aux + 1088);
  float* sms = (float*)(aux + 1152);
  u32* myp = aux + wave * 272;
  float* zex = (float*)aux;
  u16* pw = (u16*)myp;
  union F8 { u32 u[4]; short8 s; };
  const float sc = 0.17677669529663687f;
  int outb = bt * 16000;
  for (int chunk = 0; chunk < 8; ++chunk) {
    int rbase = yh * 256 + chunk * 32 + wrow * 16;
    F8 af;
    {
      int r = rbase + ln;
      int wbase = r * 20 + q * 4;
#pragma unroll
      for (int i2 = 0; i2 < 4; ++i2)
        af.u[i2] = kls[wbase + i2];
    }
    floatx4 acc[16];
#pragma unroll
    for (int ctl = 0; ctl < 16; ++ctl) {
      int r2 = (ch * 16 + ctl) * 16 + ln;
      int wb2 = r2 * 20 + q * 4;
      F8 bf;
#pragma unroll
      for (int i2 = 0; i2 < 4; ++i2)
        bf.u[i2] = kls[wb2 + i2];
      acc[ctl] = __builtin_amdgcn_mfma_f32_16x16x32_bf16(af.s, bf.s,
                (floatx4){0.f, 0.f, 0.f, 0.f}, 0, 0, 0);
    }
    if (ch == 1 && ln >= 4) {
#pragma unroll
      for (int i2 = 0; i2 < 4; ++i2) acc[15][i2] = -1e30f;   // cols >= 500
    }
    float m[4];
#pragma unroll
    for (int i2 = 0; i2 < 4; ++i2) {
      float mm = -1e30f;
#pragma unroll
      for (int ctl = 0; ctl < 16; ++ctl) mm = fmaxf(mm, acc[ctl][i2]);
#pragma unroll
      for (int d = 1; d < 16; d <<= 1) mm = fmaxf(mm, __shfl_xor(mm, d));
      m[i2] = mm;
    }
    if (ln == 0) {
#pragma unroll
      for (int i2 = 0; i2 < 4; ++i2) smx[wave * 16 + q * 4 + i2] = m[i2];
    }
    __syncthreads();   // (A) smx visible; also orders prior chunk's zex reads
    float sp[4];
#pragma unroll
    for (int i2 = 0; i2 < 4; ++i2) {
      float mm = fmaxf(m[i2], smx[(wave ^ 1) * 16 + q * 4 + i2]);
      float s = 0.f;
#pragma unroll
      for (int ctl = 0; ctl < 16; ++ctl) {
        float e = __expf((acc[ctl][i2] - mm) * sc);
        acc[ctl][i2] = e; s += e;
      }
#pragma unroll
      for (int d = 1; d < 16; d <<= 1) s += __shfl_xor(s, d);
      sp[i2] = s;
    }
    if (ln == 0) {
#pragma unroll
      for (int i2 = 0; i2 < 4; ++i2) sms[wave * 16 + q * 4 + i2] = sp[i2];
    }
    __syncthreads();   // (B) sms visible
    float inv[4];
#pragma unroll
    for (int i2 = 0; i2 < 4; ++i2)
      inv[i2] = 1.f / (sp[i2] + sms[(wave ^ 1) * 16 + q * 4 + i2]);
    floatx4 zacc[2] = {{0.f,0.f,0.f,0.f},{0.f,0.f,0.f,0.f}};
    for (int c2l = 0; c2l < 8; ++c2l) {
#pragma unroll
      for (int t2 = 0; t2 < 2; ++t2) {
        int ctl = c2l * 2 + t2;
#pragma unroll
        for (int i2 = 0; i2 < 4; ++i2)
          pw[(q * 4 + i2) * 34 + t2 * 16 + ln] = f2b(acc[ctl][i2]);
      }
      __builtin_amdgcn_wave_barrier();
      F8 pa;
#pragma unroll
      for (int i2 = 0; i2 < 4; ++i2) pa.u[i2] = myp[ln * 17 + q * 4 + i2];
      int hb = (ch * 8 + c2l) * 16 + q * 4;     // this wave's half-k slice
#pragma unroll
      for (int t2 = 0; t2 < 2; ++t2) {
        int n = t2 * 16 + ln;
        int baseT = n * 256 + (hb ^ ((n & 15) << 2));
        F8 bf;
#pragma unroll
        for (int i2 = 0; i2 < 4; ++i2) bf.u[i2] = vls[baseT + i2];
        zacc[t2] = __builtin_amdgcn_mfma_f32_16x16x32_bf16(pa.s, bf.s, zacc[t2], 0, 0, 0);
      }
      __builtin_amdgcn_wave_barrier();
    }
    __syncthreads();   // (C1) all pch reads done before zex overwrite
    if (ch) {
#pragma unroll
      for (int t2 = 0; t2 < 2; ++t2)
#pragma unroll
        for (int i2 = 0; i2 < 4; ++i2)
          zex[wrow * 544 + (q * 4 + i2) * 34 + t2 * 16 + ln] = zacc[t2][i2];
    }
    __syncthreads();   // (C2) zex visible
    if (!ch) {
#pragma unroll
      for (int t2 = 0; t2 < 2; ++t2) {
#pragma unroll
        for (int i2 = 0; i2 < 4; ++i2) {
          int r = rbase + q * 4 + i2;
          if (r < 500) {
            float vsum = zacc[t2][i2] + zex[wrow * 544 + (q * 4 + i2) * 34 + t2 * 16 + ln];
            outp[outb + r * 32 + t2 * 16 + ln] = vsum * inv[i2];
          }
        }
      }
    }
  }
}

// ---------------- K4: MFMA mlp + gate + fused ct1 -> g2 ----------------
__global__ __launch_bounds__(256, 2) void k_gate(
    const float* __restrict__ h3x, const float* __restrict__ z1x, const float* __restrict__ z2x,
    const float* __restrict__ z3x, const float* __restrict__ z4x,
    const u32* __restrict__ WBq, const float* __restrict__ mlpB,
    const float* __restrict__ ct1W, const float* __restrict__ ct1B,
    float* __restrict__ g2w)
{
  __shared__ u32 wlds[5120];       // 20 KB: 20 B-frags x 64 lanes x 4 u32
  int tid = threadIdx.x;
  for (int i = tid; i < 5120; i += 256) wlds[i] = WBq[i];
  __syncthreads();
  int lane = tid & 63, wave = tid >> 6;
  int q = lane >> 4, ln = lane & 15;
  int b = blockIdx.y;
  int n0 = blockIdx.x * 32 + wave * 8;
  int nA = n0 + (ln & 7);          // A-row n for this lane
  int tAb = ln >> 3;               // A-row t_local (0/1)
  int nD = n0 + (q & 1) * 4;       // D-row n base (n = nD + i)
  int tDb = q >> 1;                // D-row t_local
  float g2a[4][2][6];
#pragma unroll
  for (int i = 0; i < 4; ++i)
#pragma unroll
    for (int ch = 0; ch < 2; ++ch)
#pragma unroll
      for (int s = 0; s < 6; ++s) g2a[i][ch][s] = 0.f;
  float bias[4];
#pragma unroll
  for (int ct = 0; ct < 4; ++ct) bias[ct] = mlpB[ct * 16 + ln];
  union F8 { u32 u[4]; short8 s; };
  for (int tile = 0; tile < 5; ++tile) {
    int tA = tile * 2 + tAb;
    int offA = (((b * 10 + tA) * 500) + nA) * 32 + q * 8;
    floatx4 acc[4];
#pragma unroll
    for (int ct = 0; ct < 4; ++ct) acc[ct] = (floatx4){bias[ct], bias[ct], bias[ct], bias[ct]};
#pragma unroll
    for (int kt = 0; kt < 5; ++kt) {
      const float* sp = kt == 0 ? h3x : kt == 1 ? z1x : kt == 2 ? z2x : kt == 3 ? z3x : z4x;
      float4 a0 = *(const float4*)(sp + offA);
      float4 a1 = *(const float4*)(sp + offA + 4);
      F8 af;
      af.u[0] = cvtpk(a0.x, a0.y);
      af.u[1] = cvtpk(a0.z, a0.w);
      af.u[2] = cvtpk(a1.x, a1.y);
      af.u[3] = cvtpk(a1.z, a1.w);
#pragma unroll
      for (int ct = 0; ct < 4; ++ct) {
        F8 bfr;
        const u32* wp = wlds + (((kt * 4 + ct) << 6) + lane) * 4;
#pragma unroll
        for (int i2 = 0; i2 < 4; ++i2) bfr.u[i2] = wp[i2];
        acc[ct] = __builtin_amdgcn_mfma_f32_16x16x32_bf16(af.s, bfr.s, acc[ct], 0, 0, 0);
      }
    }
    int tD = tile * 2 + tDb;
    float c6[6];
#pragma unroll
    for (int s = 0; s < 6; ++s) c6[s] = ct1W[s * 10 + tD];
#pragma unroll
    for (int i = 0; i < 4; ++i) {
      float e0 = __expf(2.f * acc[0][i]);
      float g0 = ((e0 - 1.f) / (e0 + 1.f)) * (1.f / (1.f + __expf(-acc[2][i])));
      float e1 = __expf(2.f * acc[1][i]);
      float g1 = ((e1 - 1.f) / (e1 + 1.f)) * (1.f / (1.f + __expf(-acc[3][i])));
#pragma unroll
      for (int s = 0; s < 6; ++s) {
        g2a[i][0][s] += g0 * c6[s];
        g2a[i][1][s] += g1 * c6[s];
      }
    }
  }
  // combine even-t (q=0,1) and odd-t (q=2,3) partial sums: lane pair = lane ^ 32
#pragma unroll
  for (int i = 0; i < 4; ++i)
#pragma unroll
    for (int ch = 0; ch < 2; ++ch)
#pragma unroll
      for (int s = 0; s < 6; ++s)
        g2a[i][ch][s] += __shfl_xor(g2a[i][ch][s], 32);
  if (q < 2) {
#pragma unroll
    for (int i = 0; i < 4; ++i) {
      int n = nD + i;
      if (n < 500) {
#pragma unroll
        for (int ch = 0; ch < 2; ++ch) {
          int c = ln + ch * 16;
          float* gp = g2w + ((b * 32 + c) * 500 + n) * 6;
#pragma unroll
          for (int s = 0; s < 6; ++s) gp[s] = g2a[i][ch][s] + ct1B[s];
        }
      }
    }
  }
}

// ---------------- K4b: fused f1 + f2 ----------------
__global__ __launch_bounds__(256) void k_f12(const float* __restrict__ g2w,
                                             const float* __restrict__ tc1W,
                                             const float* __restrict__ c2W,
                                             float* __restrict__ f1w, float* __restrict__ f2w) {
  int blk = blockIdx.x, tid = threadIdx.x;
  if (blk < 188) {
    int i = blk * 256 + tid;
    if (i >= 48000) return;
    int b = i / 3000, rem = i - b * 3000, s = rem / 500, n = rem - s * 500;
    float a = 0.f;
    for (int c = 0; c < 32; ++c) a += g2w[((b * 32 + c) * 500 + n) * 6 + s] * tc1W[c];
    f1w[(b * 6 + s) * 500 + n] = a;
  } else {
    int pb = (blk - 188) * 4 + (tid >> 6);   // 0..511 (b,c) pairs
    int b = pb >> 5, c = pb & 31, lane = tid & 63;
    float acc[6];
#pragma unroll
    for (int t = 0; t < 6; ++t) acc[t] = 0.f;
    for (int n = lane; n < 500; n += 64) {
      float w = c2W[n];
      const float* gp = g2w + ((b * 32 + c) * 500 + n) * 6;
#pragma unroll
      for (int t = 0; t < 6; ++t) acc[t] += w * gp[t];
    }
#pragma unroll
    for (int t = 0; t < 6; ++t)
      for (int off = 32; off; off >>= 1) acc[t] += __shfl_xor(acc[t], off);
    if (lane == 0) {
#pragma unroll
      for (int t = 0; t < 6; ++t) f2w[(b * 32 + c) * 6 + t] = acc[t];
    }
  }
}

// ---------------- K5b: per-b TATT ----------------
__global__ __launch_bounds__(256) void k_tatt(
    const float* __restrict__ f1w, const float* __restrict__ tatw,
    const float* __restrict__ f2w, const float* __restrict__ tatb, const float* __restrict__ tatv,
    float* __restrict__ lg2w)
{
  __shared__ float mid[192];
  __shared__ float lgt[36];
  int b = blockIdx.x, tid = threadIdx.x;
  if (tid < 192) {
    int t = tid >> 5, c = tid & 31;
    float a = 0.f;
    const float* f1p = f1w + (b * 6 + t) * 500;
    for (int n = 0; n < 500; ++n) a += f1p[n] * tatw[n * 32 + c];
    mid[t * 32 + c] = a;
  }
  __syncthreads();
  if (tid < 36) {
    int t = tid / 6, s = tid - t * 6;
    float a = tatb[t * 6 + s];
    for (int c = 0; c < 32; ++c) a += mid[t * 32 + c] * f2w[(b * 32 + c) * 6 + s];
    lgt[t * 6 + s] = 1.f / (1.f + expf(-a));
  }
  __syncthreads();
  if (tid < 36) {
    int p = tid / 6, s = tid - p * 6;
    float a = 0.f;
#pragma unroll
    for (int t2 = 0; t2 < 6; ++t2) a += tatv[p * 6 + t2] * lgt[t2 * 6 + s];
    lg2w[(b * 6 + p) * 6 + s] = a;
  }
}

// ---------------- K5c: BN1 + softmax -> Tc ----------------
__global__ __launch_bounds__(128) void k_coefs(const float* __restrict__ lg2w,
    const float* __restrict__ bn1g, const float* __restrict__ bn1b, float* __restrict__ tcw) {
  __shared__ float mu[6], iv[6], gg[6], bb[6];
  int tid = threadIdx.x;
  if (tid < 6) {
    float s = 0.f, sq = 0.f;
    for (int b = 0; b < 16; ++b)
      for (int q = 0; q < 6; ++q) {
        float v = lg2w[(b * 6 + q) * 6 + tid];
        s += v; sq += v * v;
      }
    float m = s / 96.f;
    mu[tid] = m;
    iv[tid] = rsqrtf(sq / 96.f - m * m + 1e-5f);
    gg[tid] = bn1g[tid]; bb[tid] = bn1b[tid];
  }
  __syncthreads();
  for (int idx = tid; idx < 96; idx += 128) {
    int b = idx / 6, q = idx - b * 6;
    float v[6], mx = -1e30f;
#pragma unroll
    for (int l = 0; l < 6; ++l) {
      v[l] = (lg2w[(b * 6 + q) * 6 + l] - mu[l]) * iv[l] * gg[l] + bb[l];
      mx = fmaxf(mx, v[l]);
    }
    float tot = 0.f;
#pragma unroll
    for (int l = 0; l < 6; ++l) { v[l] = expf(v[l] - mx); tot += v[l]; }
    float inv = 1.f / tot;
#pragma unroll
    for (int l = 0; l < 6; ++l) tcw[(b * 6 + l) * 6 + q] = v[l] * inv;
  }
}

// ---------------- K6a: xo = leaky(g2@Tc)+res6, per-c sum/sumsq ----------------
__global__ __launch_bounds__(256) void k_xo(const float* __restrict__ g2w,
    const float* __restrict__ res6, const float* __restrict__ tcw,
    float* __restrict__ xow, float* __restrict__ stats) {
  __shared__ float Tcl[36];
  __shared__ float redS[32][8], redQ[32][8];
  int b = blockIdx.x, chunk = blockIdx.y, tid = threadIdx.x;
  if (tid < 36) Tcl[tid] = tcw[b * 36 + tid];
  __syncthreads();
  int c = tid & 31, sub = tid >> 5;
  int n0 = chunk * 50;
  float s = 0.f, sq = 0.f;
  for (int idx = sub; idx < 300; idx += 8) {
    int nl = idx / 6, q = idx - nl * 6;
    int n = n0 + nl;
    int base = ((b * 32 + c) * 500 + n) * 6;
    const float* gp = g2w + base;
    float xv = 0.f;
#pragma unroll
    for (int l = 0; l < 6; ++l) xv += gp[l] * Tcl[l * 6 + q];
    xv = xv > 0.f ? xv : 0.01f * xv;
    xv += res6[base + q];
    xow[base + q] = xv;
    s += xv; sq += xv * xv;
  }
  redS[c][sub] = s; redQ[c][sub] = sq;
  __syncthreads();
  if (sub == 0) {
    float ts = 0.f, tq = 0.f;
#pragma unroll
    for (int k = 0; k < 8; ++k) { ts += redS[c][k]; tq += redQ[c][k]; }
    atomicAdd(&stats[c], ts);
    atomicAdd(&stats[32 + c], tq);
  }
}

// ---------------- K6b: BN2 normalize -> FP32 out ----------------
__global__ __launch_bounds__(256) void k_out(const float* __restrict__ xow,
    const float* __restrict__ stats, const float* __restrict__ g2c, const float* __restrict__ b2c,
    float* __restrict__ out) {
  int base = (blockIdx.x * 256 + threadIdx.x) * 4;
#pragma unroll
  for (int k = 0; k < 4; ++k) {
    int i = base + k;
    int c = (i / 3000) & 31;
    float m = stats[c] * (1.f / 48000.f);
    float var = stats[32 + c] * (1.f / 48000.f) - m * m;
    out[i] = (xow[i] - m) * rsqrtf(var + 1e-5f) * g2c[c] + b2c[c];
  }
}

extern "C" void kernel_launch(void* const* d_in, const int* in_sizes, int n_in,
                              void* d_out, int out_size, void* d_ws, size_t ws_size,
                              hipStream_t stream)
{
  (void)in_sizes; (void)out_size;

  float* ws = (float*)d_ws;
  float* Af   = ws;                 // 250,000 (unused; layout kept)
  float* Wf   = Af + 250000;        // 65,536 (65,322 used)
  float* A2   = Wf + 65536;         // 250,000 (unused; layout kept)
  float* h3x  = A2 + 250000;        // 2,560,000 (B,T,N,32)
  float* z1x  = h3x + 2560000;
  float* z2x  = z1x + 2560000;
  float* z3x  = z2x + 2560000;
  float* z4x  = z3x + 2560000;
  float* res6 = z4x + 2560000;      // 1,536,000
  float* g2w  = res6 + 1536000;     // 1,536,000
  float* f1w  = g2w + 1536000;      // 48,000
  float* f2w  = f1w + 48000;        // 3,072
  float* lg2w = f2w + 3072;         // 576
  float* tcw  = lg2w + 576;         // 576
  float* stats= tcw + 576;          // 64
  float* xow  = z1x;                // reuse z1 region after k_gate
  u16*   Abf  = (u16*)g2w;          // 512x512 bf16 A pack (g2w region dead until k_gate)
  u16*   A2bf = (u16*)(g2w + 131072); // 512x512 bf16 A2 pack
  float* WTp  = g2w + 262144;       // 29,952 folded-weight + frag pack (dead before k_gate)
  u16*   WBu  = (u16*)f1w;          // 10,240 u16 mlpW B-frag pack (f1w region dead until k_f12)
  if (ws_size < (size_t)16489952 * sizeof(float)) return;  // workspace guard

  // converted-weight offsets inside Wf (cumulative over dict inputs 2..28)
  const float* c1B  = Wf + 1024;
  const float* mlpB = Wf + 48512;
  const float* ct1W = Wf + 48576;
  const float* ct1B = Wf + 48636;
  const float* tc1W = Wf + 48642;
  const float* tc2W = Wf + 48674;
  const float* tatw = Wf + 49174;
  const float* tatb = Wf + 65174;
  const float* tatv = Wf + 65210;
  const float* bn1g = Wf + 65246;
  const float* bn1b = Wf + 65252;
  const float* bn2g = Wf + 65258;
  const float* bn2b = Wf + 65290;

  Ptrs ps;
  for (int i = 0; i < 29; ++i) ps.p[i] = (i < n_in) ? d_in[i] : d_in[0];

  k_prep <<<dim3(1398),    256, 0, stream>>>(ps, Wf, Abf, WTp, WBu, stats);
  k_a2m  <<<dim3(16, 8),   256, 0, stream>>>(Abf, A2bf);
  k_front3<<<dim3(2000),   256, 0, stream>>>(ps.p[0], ps.p[25], WTp, c1B, h3x, res6);
  k_z12m <<<dim3(160, 8),  256, 0, stream>>>(h3x, Abf, A2bf, z1x, z2x);
  k_attn2<<<dim3(160, 2),  256, 0, stream>>>(h3x, h3x, z3x);
  k_attn2<<<dim3(160, 2),  256, 0, stream>>>(h3x, z3x, z4x);
  k_gate <<<dim3(16, 16),  256, 0, stream>>>(h3x, z1x, z2x, z3x, z4x,
                                             (const u32*)WBu, mlpB, ct1W, ct1B, g2w);
  k_f12  <<<dim3(316),     256, 0, stream>>>(g2w, tc1W, tc2W, f1w, f2w);
  k_tatt <<<dim3(16),      256, 0, stream>>>(f1w, tatw, f2w, tatb, tatv, lg2w);
  k_coefs<<<dim3(1),       128, 0, stream>>>(lg2w, bn1g, bn1b, tcw);
  k_xo   <<<dim3(16, 10),  256, 0, stream>>>(g2w, res6, tcw, xow, stats);
  k_out  <<<dim3(1500),    256, 0, stream>>>(xow, stats, bn2g, bn2b, (float*)d_out);
}

// Round 16
// 386.301 us; speedup vs baseline: 1.0787x; 1.0145x over previous
//
#include <hip/hip_runtime.h>

typedef unsigned short u16;
typedef unsigned int u32;

__device__ __forceinline__ float b2f(u16 v) { return __uint_as_float((u32)v << 16); }
__device__ __forceinline__ float lopart(u32 u) { return __uint_as_float(u << 16); }
__device__ __forceinline__ float hipart(u32 u) { return __uint_as_float(u & 0xffff0000u); }
__device__ __forceinline__ u16 f2b(float f) {
  u32 u = __float_as_uint(f);
  u32 r = u + 0x7fffu + ((u >> 16) & 1u);
  return (u16)(r >> 16);
}
__device__ __forceinline__ u32 pk2(float a, float b) {
  return (u32)f2b(a) | ((u32)f2b(b) << 16);
}
__device__ __forceinline__ u32 cvtpk(float lo, float hi) {
  u32 r;
  asm("v_cvt_pk_bf16_f32 %0, %1, %2" : "=v"(r) : "v"(lo), "v"(hi));
  return r;
}
__device__ __forceinline__ float rd(const void* p, int i, bool BF) {
  return BF ? b2f(((const u16*)p)[i]) : ((const float*)p)[i];
}

struct Ptrs { const void* p[29]; };

typedef __attribute__((ext_vector_type(8))) short short8;
typedef __attribute__((ext_vector_type(4))) float floatx4;

// ---------------- K-prep: fused cvt + A-pack + folded-weight prep + MFMA frag packs + stats ----
__global__ __launch_bounds__(256) void k_prep(Ptrs ps, float* __restrict__ Wf,
                                              u16* __restrict__ Abf, float* __restrict__ WT,
                                              u16* __restrict__ WBu, float* __restrict__ stats) {
  bool BF = ((*(const u32*)ps.p[25]) & 0xffffu) != 0;
  int blk = blockIdx.x, tid = threadIdx.x;
  const void* p2  = ps.p[2];
  const void* p4  = ps.p[4];
  const void* p5  = ps.p[5];
  const void* p6  = ps.p[6];
  const void* p7  = ps.p[7];
  const void* p8  = ps.p[8];
  const void* p9  = ps.p[9];
  const void* p10 = ps.p[10];
  const void* p11 = ps.p[11];
  const void* p12 = ps.p[12];
  const void* p13 = ps.p[13];
  const void* p14 = ps.p[14];
  const void* p15 = ps.p[15];
  const void* p16 = ps.p[16];
  if (blk < 256) {
    int j = blk * 256 + tid;
    if (j >= 65322) return;
    const int SZ[27] = {1024,32,2048,64,12288,64,12288,64,4096,64,4096,64,2048,32,
                        10240,64,60,6,32,500,16000,36,36,6,6,32,32};
    int t = 0, off = 0;
#pragma unroll
    for (int k = 0; k < 27; ++k) {
      if (t == k && j >= off + SZ[k]) { off += SZ[k]; t = k + 1; }
    }
    Wf[j] = rd(ps.p[2 + t], j - off, BF);
  } else if (blk < 1280) {
    int i = (blk - 256) * 256 + tid;
    int r = i >> 9, v = i & 511;
    bool in = (r < 500) && (v < 500);
    u16 o = 0;
    if (in) o = BF ? ((const u16*)ps.p[1])[r * 500 + v] : f2b(((const float*)ps.p[1])[r * 500 + v]);
    Abf[i] = o;
  } else if (blk < 1366) {
    int i = (blk - 1280) * 256 + tid;
    if (i < 1024) {
      WT[i] = rd(p2, (i & 31) * 32 + (i >> 5), BF);
    } else if (i >= 9600 && i < 9664) {
      int o = i - 9600;
      float s = rd(p11, o, BF);
      for (int i2 = 0; i2 < 64; ++i2)
        s += rd(p10, o * 64 + i2, BF) * rd(p5, i2, BF);
      WT[i] = s;
    } else if (i >= 9664 && i < 11712) {
      int j2 = i - 9664;
      int jj = j2 >> 5, c = j2 & 31;
      float s = 0.f;
      for (int o2 = 0; o2 < 64; ++o2)
        s += rd(p14, c * 64 + o2, BF) * rd(p12, o2 * 64 + jj, BF);
      WT[i] = s;
    } else if (i >= 11712 && i < 11744) {
      int c = i - 11712;
      float s = rd(p15, c, BF);
      for (int o2 = 0; o2 < 64; ++o2)
        s += rd(p14, c * 64 + o2, BF) * rd(p13, o2, BF);
      WT[i] = s;
    } else if (i >= 11744 && i < 21984) {
      int j2 = i - 11744;
      int j = j2 & 7, lanev = (j2 >> 3) & 63, ct = (j2 >> 9) & 3, kt = j2 >> 11;
      int qv = lanev >> 4, lnv = lanev & 15;
      int o = ct * 16 + lnv, k = kt * 32 + qv * 8 + j;
      WBu[j2] = f2b(rd(p16, o * 160 + k, BF));
    }
  } else if (blk < 1390) {
    // WQK A-frags: tile mt (0-3 q rows, 4-7 k rows), K-step ks (= tap), 16x32 each
    int idx = (blk - 1366) * 256 + tid;   // < 6144
    int i2 = idx & 3, lanev = (idx >> 2) & 63, mt = (idx >> 8) & 7, ks = idx >> 11;
    int q2 = lanev >> 4, ln = lanev & 15;
    int o = (mt & 3) * 16 + ln;
    const void* src = (mt >= 4) ? p8 : p6;
    int kb0 = q2 * 8 + 2 * i2;
    float v0 = 0.f, v1 = 0.f;
    for (int i3 = 0; i3 < 64; ++i3) {
      float w = rd(src, o * 192 + i3 * 3 + ks, BF);
      v0 += w * rd(p4, i3 * 32 + kb0, BF);
      v1 += w * rd(p4, i3 * 32 + kb0 + 1, BF);
    }
    ((u32*)WT)[22016 + idx] = pk2(v0, v1);
  } else if (blk < 1394) {
    // WV A-frags: 4 tiles of v[64x32] fold
    int idx = (blk - 1390) * 256 + tid;   // < 1024
    int i2 = idx & 3, lanev = (idx >> 2) & 63, mt = idx >> 8;
    int o = mt * 16 + (lanev & 15);
    int kb0 = (lanev >> 4) * 8 + 2 * i2;
    float v0 = 0.f, v1 = 0.f;
    for (int i3 = 0; i3 < 64; ++i3) {
      float w = rd(p10, o * 64 + i3, BF);
      v0 += w * rd(p4, i3 * 32 + kb0, BF);
      v1 += w * rd(p4, i3 * 32 + kb0 + 1, BF);
    }
    ((u32*)WT)[28160 + idx] = pk2(v0, v1);
  } else if (blk < 1397) {
    // per-t-class bias tables: cls 0 (t==0): b+S1+S2; 1 (mid): b+S0+S1+S2; 2 (t==9): b+S0+S1
    int j = (blk - 1394) * 256 + tid;     // < 768
    if (j < 768) {
      bool isK = j >= 384;
      int jj = isK ? j - 384 : j;
      int cls = jj >> 6, o = jj & 63;
      const void* srcW = isK ? p8 : p6;
      const void* srcB = isK ? p9 : p7;
      float S0 = 0.f, S1 = 0.f, S2 = 0.f;
      for (int i3 = 0; i3 < 64; ++i3) {
        float tb = rd(p5, i3, BF);
        S0 += rd(srcW, o * 192 + i3 * 3 + 0, BF) * tb;
        S1 += rd(srcW, o * 192 + i3 * 3 + 1, BF) * tb;
        S2 += rd(srcW, o * 192 + i3 * 3 + 2, BF) * tb;
      }
      float val = rd(srcB, o, BF) + S1 + (cls > 0 ? S0 : 0.f) + (cls < 2 ? S2 : 0.f);
      WT[29184 + j] = val;
    }
  } else {
    if (tid < 64) stats[tid] = 0.f;
  }
}

// ---------------- K0m: MFMA A2 = A @ A (bf16 in/out, fp32 accumulate) ----------------
__global__ __launch_bounds__(256, 4) void k_a2m(const u16* __restrict__ Abf,
                                                u16* __restrict__ A2bf) {
  __shared__ u32 blsT[8192];     // [c][k-pair] swizzled (32 KB), c = local col
  int tid = threadIdx.x;
  int c0 = blockIdx.x * 32;
  for (int i = tid; i < 8192; i += 256) {
    int c = i & 31, h = i >> 5;
    int r0 = 2 * h;
    u32 lo = Abf[r0 * 512 + c0 + c];
    u32 hi = Abf[(r0 + 1) * 512 + c0 + c];
    blsT[c * 256 + (((h & 0xFC) ^ ((c & 15) << 2)) | (h & 3))] = lo | (hi << 16);
  }
  __syncthreads();
  int lane = tid & 63, wave = tid >> 6;
  int q = lane >> 4, ln = lane & 15;
  int rbase = blockIdx.y * 64 + wave * 16;
  const u32* Au = (const u32*)Abf;
  int arow = (rbase + ln) * 256;
  union F8 { u32 u[4]; short8 s; };
  floatx4 acc[2] = {{0.f,0.f,0.f,0.f},{0.f,0.f,0.f,0.f}};
  for (int c2 = 0; c2 < 16; ++c2) {
    int hb = c2 * 16 + q * 4;
    F8 af;
#pragma unroll
    for (int i2 = 0; i2 < 4; ++i2) af.u[i2] = Au[arow + hb + i2];
#pragma unroll
    for (int t2 = 0; t2 < 2; ++t2) {
      int c = t2 * 16 + ln;
      int baseT = c * 256 + (hb ^ ((c & 15) << 2));
      F8 bf;
#pragma unroll
      for (int i2 = 0; i2 < 4; ++i2) bf.u[i2] = blsT[baseT + i2];
      acc[t2] = __builtin_amdgcn_mfma_f32_16x16x32_bf16(af.s, bf.s, acc[t2], 0, 0, 0);
    }
  }
#pragma unroll
  for (int t2 = 0; t2 < 2; ++t2) {
#pragma unroll
    for (int i2 = 0; i2 < 4; ++i2) {
      int r = rbase + q * 4 + i2;
      A2bf[r * 512 + c0 + t2 * 16 + ln] = f2b(acc[t2][i2]);
    }
  }
}

// ---------------- K1: frontend, qkv via MFMA; one (b,n) pair per WAVE, zero block barriers --------
__global__ __launch_bounds__(256, 5) void k_front3(
    const void* __restrict__ xraw, const void* __restrict__ g1, const float* __restrict__ WT,
    const float* __restrict__ c1B,
    float* __restrict__ h3x, float* __restrict__ res6)
{
  __shared__ __align__(16) float arena[4][1680];
  int tid = threadIdx.x;
  int wave = tid >> 6, lane = tid & 63;
  float* Aw = arena[wave];
  int pair = blockIdx.x * 4 + wave;
  int b = pair / 500, n = pair - b * 500;

  const float* c1T  = WT;
  const float* bvp  = WT + 9600;
  const float* otT  = WT + 9664;
  const float* botp = WT + 11712;
  const u32* WQKf = (const u32*)WT + 22016;
  const u32* WVf  = (const u32*)WT + 28160;
  const float* bq3 = WT + 29184;
  const float* bk3 = WT + 29568;

  // ---- x -> LDS rows [c*12 + t] (convert at point of use)
  {
    bool BF = ((*(const u32*)g1) & 0xffffu) != 0;
    int c0 = lane >> 1, hf = (lane & 1) * 5;
    int base = ((b * 32 + c0) * 500 + n) * 10 + hf;
    float* dst = Aw + c0 * 12 + hf;
    if (BF) {
      const u16* xp = (const u16*)xraw + base;
#pragma unroll
      for (int k2 = 0; k2 < 5; ++k2) dst[k2] = b2f(xp[k2]);
    } else {
      const float* xp = (const float*)xraw + base;
#pragma unroll
      for (int k2 = 0; k2 < 5; ++k2) dst[k2] = xp[k2];
    }
  }
  __builtin_amdgcn_wave_barrier();

  int cl = lane & 31, th = lane >> 5;
  int q2 = lane >> 4, ln15 = lane & 15;

  // ---- residual: lane=(c, th), 3 time outputs each
  {
    float r0 = c1B[cl], r1 = r0, r2 = r0;
#pragma unroll 4
    for (int i = 0; i < 32; ++i) {
      float w = c1T[i * 32 + cl];
      const float* xr = Aw + i * 12 + 4 + th * 3;
      r0 += w * xr[0]; r1 += w * xr[1]; r2 += w * xr[2];
    }
    float* rp = res6 + ((b * 32 + cl) * 500 + n) * 6 + th * 3;
    rp[0] = r0; rp[1] = r1; rp[2] = r2;
  }

  // ---- build xT3 (B matrix, bf16): row t, col k = tau*32+c -> xpad[c][t-1+tau]
  {
    u32* xT3u = (u32*)Aw + 384;
    for (int e = lane; e < 480; e += 64) {
      int t = e / 48, col2 = e - t * 48;
      int kk0 = col2 * 2, kk1 = kk0 + 1;
      int tau0 = kk0 >> 5, c0 = kk0 & 31;
      int tau1 = kk1 >> 5, c1 = kk1 & 31;
      int tx0 = t - 1 + tau0, tx1 = t - 1 + tau1;
      float f0 = (tx0 >= 0 && tx0 < 10) ? Aw[c0 * 12 + tx0] : 0.f;
      float f1 = (tx1 >= 0 && tx1 < 10) ? Aw[c1 * 12 + tx1] : 0.f;
      xT3u[t * 52 + col2] = cvtpk(f0, f1);
    }
  }
  __builtin_amdgcn_wave_barrier();

  // ---- qkv via MFMA: [q;k] = Wqk[128x96] @ xpad ; v = Wv[64x32] @ x (ks=1 slice)
  union F8 { u32 u[4]; short8 s; };
  floatx4 aq[4] = {{0.f,0.f,0.f,0.f},{0.f,0.f,0.f,0.f},{0.f,0.f,0.f,0.f},{0.f,0.f,0.f,0.f}};
  floatx4 ak[4] = {{0.f,0.f,0.f,0.f},{0.f,0.f,0.f,0.f},{0.f,0.f,0.f,0.f},{0.f,0.f,0.f,0.f}};
  floatx4 av[4] = {{0.f,0.f,0.f,0.f},{0.f,0.f,0.f,0.f},{0.f,0.f,0.f,0.f},{0.f,0.f,0.f,0.f}};
  {
    const u32* xT3u = (const u32*)Aw + 384;
#pragma unroll
    for (int ks = 0; ks < 3; ++ks) {
      F8 bfr;
      const u32* bp = xT3u + ln15 * 52 + ks * 16 + q2 * 4;
#pragma unroll
      for (int i2 = 0; i2 < 4; ++i2) bfr.u[i2] = bp[i2];
#pragma unroll
      for (int mt = 0; mt < 4; ++mt) {
        F8 afr;
        const u32* ap = WQKf + ((ks * 8 + mt) * 64 + lane) * 4;
#pragma unroll
        for (int i2 = 0; i2 < 4; ++i2) afr.u[i2] = ap[i2];
        aq[mt] = __builtin_amdgcn_mfma_f32_16x16x32_bf16(afr.s, bfr.s, aq[mt], 0, 0, 0);
      }
#pragma unroll
      for (int mt = 0; mt < 4; ++mt) {
        F8 afr;
        const u32* ap = WQKf + ((ks * 8 + 4 + mt) * 64 + lane) * 4;
#pragma unroll
        for (int i2 = 0; i2 < 4; ++i2) afr.u[i2] = ap[i2];
        ak[mt] = __builtin_amdgcn_mfma_f32_16x16x32_bf16(afr.s, bfr.s, ak[mt], 0, 0, 0);
      }
      if (ks == 1) {
#pragma unroll
        for (int mt = 0; mt < 4; ++mt) {
          F8 afr;
          const u32* ap = WVf + (mt * 64 + lane) * 4;
#pragma unroll
          for (int i2 = 0; i2 < 4; ++i2) afr.u[i2] = ap[i2];
          av[mt] = __builtin_amdgcn_mfma_f32_16x16x32_bf16(afr.s, bfr.s, av[mt], 0, 0, 0);
        }
      }
    }
  }
  __builtin_amdgcn_wave_barrier();
  // ---- bias + spill q,k,v bf16 in [o][t] layout (cols t>=10 discarded)
  if (ln15 < 10) {
    int t = ln15;
    int cls = (t == 0) ? 0 : ((t == 9) ? 2 : 1);
    const float* bq = bq3 + cls * 64;
    const float* bk = bk3 + cls * 64;
    u16* q16 = (u16*)Aw;
    u16* k16 = (u16*)((u32*)Aw + 320);
    u16* v16 = (u16*)((u32*)Aw + 960);
#pragma unroll
    for (int mt = 0; mt < 4; ++mt) {
#pragma unroll
      for (int i2 = 0; i2 < 4; ++i2) {
        int o = mt * 16 + q2 * 4 + i2;
        q16[o * 10 + t] = f2b(aq[mt][i2] + bq[o]);
        k16[o * 10 + t] = f2b(ak[mt][i2] + bk[o]);
        v16[o * 10 + t] = f2b(av[mt][i2] + bvp[o]);
      }
    }
  }
  __builtin_amdgcn_wave_barrier();

  // ---- scores + softmax: 80 (head,row) rows over 2 passes; P bf16 -> [1280,1680)
  {
    const u32* qb = (const u32*)Aw;
    const u32* kb = (const u32*)Aw + 320;
#pragma unroll
    for (int pass = 0; pass < 2; ++pass) {
      int row = pass * 64 + lane;
      if (row < 80) {
        int h8 = (row / 10) * 8, r = row - (row / 10) * 10;
        int rm = r >> 1, rs = r & 1;
        float sv[10];
#pragma unroll
        for (int s = 0; s < 10; ++s) sv[s] = 0.f;
#pragma unroll 2
        for (int d = 0; d < 8; ++d) {
          int jj = h8 + d;
          u32 qu = qb[jj * 5 + rm];
          float qv = rs ? hipart(qu) : lopart(qu);
          const u32* kp2 = kb + jj * 5;
          u32 ka0 = kp2[0], ka1 = kp2[1], ka2 = kp2[2], ka3 = kp2[3], ka4 = kp2[4];
          sv[0] += qv * lopart(ka0); sv[1] += qv * hipart(ka0);
          sv[2] += qv * lopart(ka1); sv[3] += qv * hipart(ka1);
          sv[4] += qv * lopart(ka2); sv[5] += qv * hipart(ka2);
          sv[6] += qv * lopart(ka3); sv[7] += qv * hipart(ka3);
          sv[8] += qv * lopart(ka4); sv[9] += qv * hipart(ka4);
        }
        const float sc_ = 0.35355339059327373f;
        float mx = sv[0];
#pragma unroll
        for (int s = 1; s < 10; ++s) mx = fmaxf(mx, sv[s]);
        float tot = 0.f, ev[10];
#pragma unroll
        for (int s = 0; s < 10; ++s) { ev[s] = __expf((sv[s] - mx) * sc_); tot += ev[s]; }
        float inv = 1.f / tot;
        u32* pp = (u32*)Aw + 1280 + row * 5;
#pragma unroll
        for (int m2 = 0; m2 < 5; ++m2)
          pp[m2] = cvtpk(ev[2 * m2] * inv, ev[2 * m2 + 1] * inv);
      }
    }
  }
  __builtin_amdgcn_wave_barrier();

  // ---- PV: lane = j (head h=j>>3), v from LDS bf16, P bf16 broadcast; o -> [0,768) f32
  {
    float vrL[10];
    const u32* vp = (const u32*)Aw + 960 + lane * 5;
#pragma unroll
    for (int m2 = 0; m2 < 5; ++m2) {
      u32 w = vp[m2];
      vrL[2 * m2] = lopart(w); vrL[2 * m2 + 1] = hipart(w);
    }
    const u32* pb = (const u32*)Aw + 1280 + (lane >> 3) * 50;
    float orr[10];
#pragma unroll
    for (int t = 0; t < 10; ++t) {
      const u32* pr = pb + t * 5;
      float a = 0.f;
#pragma unroll
      for (int m2 = 0; m2 < 5; ++m2) {
        u32 w = pr[m2];
        a += lopart(w) * vrL[2 * m2] + hipart(w) * vrL[2 * m2 + 1];
      }
      orr[t] = a;
    }
    float* op = Aw + lane * 12;
    *(float4*)op       = make_float4(orr[0], orr[1], orr[2], orr[3]);
    *(float4*)(op + 4) = make_float4(orr[4], orr[5], orr[6], orr[7]);
    *(float2*)(op + 8) = make_float2(orr[8], orr[9]);
  }
  __builtin_amdgcn_wave_barrier();

  // ---- fused lino+te2 + h3x store: lane = (c, th), 5 t's each
  {
    float bt2 = botp[cl];
    float a5[5];
#pragma unroll
    for (int k2 = 0; k2 < 5; ++k2) a5[k2] = bt2;
    const float* tp0 = otT + cl;
    const float* base = Aw + th * 5;
#pragma unroll 2
    for (int j = 0; j < 64; ++j) {
      float w = tp0[j * 32];
      const float* lp = base + j * 12;
#pragma unroll
      for (int k2 = 0; k2 < 5; ++k2) a5[k2] += w * lp[k2];
    }
    int t0 = th * 5;
#pragma unroll
    for (int k2 = 0; k2 < 5; ++k2)
      h3x[((b * 10 + t0 + k2) * 500 + n) * 32 + cl] = a5[k2];
  }
}

// ---------------- K2: MFMA z1 = A @ XT, z2 = A2 @ XT ----------------
__global__ __launch_bounds__(256, 4) void k_z12m(const float* __restrict__ h3x,
    const u16* __restrict__ Abf, const u16* __restrict__ A2bf,
    float* __restrict__ z1x, float* __restrict__ z2x) {
  __shared__ u32 xlsT[8192];     // [n][half-row] pairs, swizzled (32 KB)
  int tid = threadIdx.x, bt = blockIdx.x;
  const float* src = h3x + bt * 16000;
  for (int i = tid; i < 8192; i += 256) {
    int n = i & 31, h = i >> 5;
    int r0 = 2 * h;
    float v0 = (r0 < 500) ? src[r0 * 32 + n] : 0.f;
    float v1 = (r0 + 1 < 500) ? src[(r0 + 1) * 32 + n] : 0.f;
    xlsT[n * 256 + (((h & 0xFC) ^ ((n & 15) << 2)) | (h & 3))] = cvtpk(v0, v1);
  }
  __syncthreads();
  int lane = tid & 63, wave = tid >> 6;
  int q = lane >> 4, ln = lane & 15;
  int rbase = blockIdx.y * 64 + wave * 16;
  const u32* Au = (const u32*)Abf;
  const u32* A2u = (const u32*)A2bf;
  int arow = (rbase + ln) * 256;
  union F8 { u32 u[4]; short8 s; };
  floatx4 acc1[2] = {{0.f,0.f,0.f,0.f},{0.f,0.f,0.f,0.f}};
  floatx4 acc2[2] = {{0.f,0.f,0.f,0.f},{0.f,0.f,0.f,0.f}};
  for (int c2 = 0; c2 < 16; ++c2) {
    int hb = c2 * 16 + q * 4;         // aligned half-row base for this quad's k-slice
    F8 a1f, a2f;
#pragma unroll
    for (int i2 = 0; i2 < 4; ++i2) {
      a1f.u[i2] = Au[arow + hb + i2];
      a2f.u[i2] = A2u[arow + hb + i2];
    }
#pragma unroll
    for (int t2 = 0; t2 < 2; ++t2) {
      int n = t2 * 16 + ln;
      int baseT = n * 256 + (hb ^ ((n & 15) << 2));
      F8 bf;
#pragma unroll
      for (int i2 = 0; i2 < 4; ++i2) bf.u[i2] = xlsT[baseT + i2];
      acc1[t2] = __builtin_amdgcn_mfma_f32_16x16x32_bf16(a1f.s, bf.s, acc1[t2], 0, 0, 0);
      acc2[t2] = __builtin_amdgcn_mfma_f32_16x16x32_bf16(a2f.s, bf.s, acc2[t2], 0, 0, 0);
    }
  }
  int outb = bt * 16000;
#pragma unroll
  for (int t2 = 0; t2 < 2; ++t2) {
#pragma unroll
    for (int i2 = 0; i2 < 4; ++i2) {
      int r = rbase + q * 4 + i2;
      if (r < 500) {
        z1x[outb + r * 32 + t2 * 16 + ln] = acc1[t2][i2];
        z2x[outb + r * 32 + t2 * 16 + ln] = acc2[t2][i2];
      }
    }
  }
}

// ---------------- K3: MFMA fused attention: out = softmax(K K^T / sqrt(32)) @ V ----------------
// WAVE-INDEPENDENT ONLINE-SOFTMAX: grid (160,2); K (stride-20) + V^T (z12m) resident.
// Each wave owns 16 score-rows and walks the two 256-col k-halves sequentially with
// online max/sum (zacc rescale). No cross-wave exchange -> ZERO block barriers in the
// main loop (pch is per-wave). LDS ~76.2 KB -> 2 blocks/CU.
__global__ __launch_bounds__(256, 2) void k_attn2(const float* __restrict__ keys,
                                                  const float* __restrict__ vals,
                                                  float* __restrict__ outp) {
  __shared__ u32 kls[10240];       // K rows stride-20 (40 KB), resident
  __shared__ u32 vls[8192];        // V^T z12m swizzled (32 KB), resident
  __shared__ u32 pch[1088];        // per-wave P chunk: 4 x 272
  int tid = threadIdx.x, bt = blockIdx.x, yh = blockIdx.y;
  const float* kb = keys + bt * 16000;
  const float* vb = vals + bt * 16000;
  for (int i = tid; i < 8192; i += 256) {
    int r = i >> 4, cu = i & 15;
    float2 g = make_float2(0.f, 0.f);
    if (r < 500) g = *(const float2*)(kb + r * 32 + cu * 2);
    kls[r * 20 + cu] = cvtpk(g.x, g.y);
    int n = i & 31, h = i >> 5;
    int r0 = 2 * h;
    float v0 = (r0 < 500) ? vb[r0 * 32 + n] : 0.f;
    float v1 = (r0 + 1 < 500) ? vb[(r0 + 1) * 32 + n] : 0.f;
    vls[n * 256 + (((h & 0xFC) ^ ((n & 15) << 2)) | (h & 3))] = cvtpk(v0, v1);
  }
  __syncthreads();
  int lane = tid & 63, wave = tid >> 6;
  int q = lane >> 4, ln = lane & 15;
  u32* myp = pch + wave * 272;
  u16* pw = (u16*)myp;
  union F8 { u32 u[4]; short8 s; };
  const float sc = 0.17677669529663687f;
  int outb = bt * 16000;
  for (int chunk = 0; chunk < 4; ++chunk) {
    int rbase = yh * 256 + chunk * 64 + wave * 16;
    F8 af;
    {
      int r = rbase + ln;
      int wbase = r * 20 + q * 4;
#pragma unroll
      for (int i2 = 0; i2 < 4; ++i2) af.u[i2] = kls[wbase + i2];
    }
    floatx4 zacc[2] = {{0.f,0.f,0.f,0.f},{0.f,0.f,0.f,0.f}};
    float mrun[4], srun[4];
#pragma unroll 1
    for (int kh = 0; kh < 2; ++kh) {
      floatx4 acc[16];
#pragma unroll
      for (int ctl = 0; ctl < 16; ++ctl) {
        int r2 = (kh * 16 + ctl) * 16 + ln;
        int wb2 = r2 * 20 + q * 4;
        F8 bf;
#pragma unroll
        for (int i2 = 0; i2 < 4; ++i2) bf.u[i2] = kls[wb2 + i2];
        acc[ctl] = __builtin_amdgcn_mfma_f32_16x16x32_bf16(af.s, bf.s,
                  (floatx4){0.f, 0.f, 0.f, 0.f}, 0, 0, 0);
      }
      if (kh == 1 && ln >= 4) {
#pragma unroll
        for (int i2 = 0; i2 < 4; ++i2) acc[15][i2] = -1e30f;   // cols >= 500
      }
#pragma unroll
      for (int i2 = 0; i2 < 4; ++i2) {
        float mm = -1e30f;
#pragma unroll
        for (int ctl = 0; ctl < 16; ++ctl) mm = fmaxf(mm, acc[ctl][i2]);
#pragma unroll
        for (int d = 1; d < 16; d <<= 1) mm = fmaxf(mm, __shfl_xor(mm, d));
        float M, r0s;
        if (kh == 0) { M = mm; r0s = 1.f; }
        else { M = fmaxf(mrun[i2], mm); r0s = __expf((mrun[i2] - M) * sc); }
        float s = 0.f;
#pragma unroll
        for (int ctl = 0; ctl < 16; ++ctl) {
          float e = __expf((acc[ctl][i2] - M) * sc);
          acc[ctl][i2] = e; s += e;
        }
#pragma unroll
        for (int d = 1; d < 16; d <<= 1) s += __shfl_xor(s, d);
        if (kh == 0) { mrun[i2] = M; srun[i2] = s; }
        else {
          srun[i2] = srun[i2] * r0s + s;
          zacc[0][i2] *= r0s;
          zacc[1][i2] *= r0s;
        }
      }
      for (int c2l = 0; c2l < 8; ++c2l) {
#pragma unroll
        for (int t2 = 0; t2 < 2; ++t2) {
          int ctl = c2l * 2 + t2;
#pragma unroll
          for (int i2 = 0; i2 < 4; ++i2)
            pw[(q * 4 + i2) * 34 + t2 * 16 + ln] = f2b(acc[ctl][i2]);
        }
        __builtin_amdgcn_wave_barrier();
        F8 pa;
#pragma unroll
        for (int i2 = 0; i2 < 4; ++i2) pa.u[i2] = myp[ln * 17 + q * 4 + i2];
        int hb = (kh * 8 + c2l) * 16 + q * 4;   // this half's k-slice
#pragma unroll
        for (int t2 = 0; t2 < 2; ++t2) {
          int n = t2 * 16 + ln;
          int baseT = n * 256 + (hb ^ ((n & 15) << 2));
          F8 bf;
#pragma unroll
          for (int i2 = 0; i2 < 4; ++i2) bf.u[i2] = vls[baseT + i2];
          zacc[t2] = __builtin_amdgcn_mfma_f32_16x16x32_bf16(pa.s, bf.s, zacc[t2], 0, 0, 0);
        }
        __builtin_amdgcn_wave_barrier();
      }
    }
    float inv[4];
#pragma unroll
    for (int i2 = 0; i2 < 4; ++i2) inv[i2] = 1.f / srun[i2];
#pragma unroll
    for (int t2 = 0; t2 < 2; ++t2) {
#pragma unroll
      for (int i2 = 0; i2 < 4; ++i2) {
        int r = rbase + q * 4 + i2;
        if (r < 500) outp[outb + r * 32 + t2 * 16 + ln] = zacc[t2][i2] * inv[i2];
      }
    }
  }
}

// ---------------- K4: MFMA mlp + gate + fused ct1 -> g2 ----------------
__global__ __launch_bounds__(256, 2) void k_gate(
    const float* __restrict__ h3x, const float* __restrict__ z1x, const float* __restrict__ z2x,
    const float* __restrict__ z3x, const float* __restrict__ z4x,
    const u32* __restrict__ WBq, const float* __restrict__ mlpB,
    const float* __restrict__ ct1W, const float* __restrict__ ct1B,
    float* __restrict__ g2w)
{
  __shared__ u32 wlds[5120];       // 20 KB: 20 B-frags x 64 lanes x 4 u32
  int tid = threadIdx.x;
  for (int i = tid; i < 5120; i += 256) wlds[i] = WBq[i];
  __syncthreads();
  int lane = tid & 63, wave = tid >> 6;
  int q = lane >> 4, ln = lane & 15;
  int b = blockIdx.y;
  int n0 = blockIdx.x * 32 + wave * 8;
  int nA = n0 + (ln & 7);          // A-row n for this lane
  int tAb = ln >> 3;               // A-row t_local (0/1)
  int nD = n0 + (q & 1) * 4;       // D-row n base (n = nD + i)
  int tDb = q >> 1;                // D-row t_local
  float g2a[4][2][6];
#pragma unroll
  for (int i = 0; i < 4; ++i)
#pragma unroll
    for (int ch = 0; ch < 2; ++ch)
#pragma unroll
      for (int s = 0; s < 6; ++s) g2a[i][ch][s] = 0.f;
  float bias[4];
#pragma unroll
  for (int ct = 0; ct < 4; ++ct) bias[ct] = mlpB[ct * 16 + ln];
  union F8 { u32 u[4]; short8 s; };
  for (int tile = 0; tile < 5; ++tile) {
    int tA = tile * 2 + tAb;
    int offA = (((b * 10 + tA) * 500) + nA) * 32 + q * 8;
    floatx4 acc[4];
#pragma unroll
    for (int ct = 0; ct < 4; ++ct) acc[ct] = (floatx4){bias[ct], bias[ct], bias[ct], bias[ct]};
#pragma unroll
    for (int kt = 0; kt < 5; ++kt) {
      const float* sp = kt == 0 ? h3x : kt == 1 ? z1x : kt == 2 ? z2x : kt == 3 ? z3x : z4x;
      float4 a0 = *(const float4*)(sp + offA);
      float4 a1 = *(const float4*)(sp + offA + 4);
      F8 af;
      af.u[0] = cvtpk(a0.x, a0.y);
      af.u[1] = cvtpk(a0.z, a0.w);
      af.u[2] = cvtpk(a1.x, a1.y);
      af.u[3] = cvtpk(a1.z, a1.w);
#pragma unroll
      for (int ct = 0; ct < 4; ++ct) {
        F8 bfr;
        const u32* wp = wlds + (((kt * 4 + ct) << 6) + lane) * 4;
#pragma unroll
        for (int i2 = 0; i2 < 4; ++i2) bfr.u[i2] = wp[i2];
        acc[ct] = __builtin_amdgcn_mfma_f32_16x16x32_bf16(af.s, bfr.s, acc[ct], 0, 0, 0);
      }
    }
    int tD = tile * 2 + tDb;
    float c6[6];
#pragma unroll
    for (int s = 0; s < 6; ++s) c6[s] = ct1W[s * 10 + tD];
#pragma unroll
    for (int i = 0; i < 4; ++i) {
      float e0 = __expf(2.f * acc[0][i]);
      float g0 = ((e0 - 1.f) / (e0 + 1.f)) * (1.f / (1.f + __expf(-acc[2][i])));
      float e1 = __expf(2.f * acc[1][i]);
      float g1 = ((e1 - 1.f) / (e1 + 1.f)) * (1.f / (1.f + __expf(-acc[3][i])));
#pragma unroll
      for (int s = 0; s < 6; ++s) {
        g2a[i][0][s] += g0 * c6[s];
        g2a[i][1][s] += g1 * c6[s];
      }
    }
  }
  // combine even-t (q=0,1) and odd-t (q=2,3) partial sums: lane pair = lane ^ 32
#pragma unroll
  for (int i = 0; i < 4; ++i)
#pragma unroll
    for (int ch = 0; ch < 2; ++ch)
#pragma unroll
      for (int s = 0; s < 6; ++s)
        g2a[i][ch][s] += __shfl_xor(g2a[i][ch][s], 32);
  if (q < 2) {
#pragma unroll
    for (int i = 0; i < 4; ++i) {
      int n = nD + i;
      if (n < 500) {
#pragma unroll
        for (int ch = 0; ch < 2; ++ch) {
          int c = ln + ch * 16;
          float* gp = g2w + ((b * 32 + c) * 500 + n) * 6;
#pragma unroll
          for (int s = 0; s < 6; ++s) gp[s] = g2a[i][ch][s] + ct1B[s];
        }
      }
    }
  }
}

// ---------------- K4b: fused f1 + f2 ----------------
__global__ __launch_bounds__(256) void k_f12(const float* __restrict__ g2w,
                                             const float* __restrict__ tc1W,
                                             const float* __restrict__ c2W,
                                             float* __restrict__ f1w, float* __restrict__ f2w) {
  int blk = blockIdx.x, tid = threadIdx.x;
  if (blk < 188) {
    int i = blk * 256 + tid;
    if (i >= 48000) return;
    int b = i / 3000, rem = i - b * 3000, s = rem / 500, n = rem - s * 500;
    float a = 0.f;
    for (int c = 0; c < 32; ++c) a += g2w[((b * 32 + c) * 500 + n) * 6 + s] * tc1W[c];
    f1w[(b * 6 + s) * 500 + n] = a;
  } else {
    int pb = (blk - 188) * 4 + (tid >> 6);   // 0..511 (b,c) pairs
    int b = pb >> 5, c = pb & 31, lane = tid & 63;
    float acc[6];
#pragma unroll
    for (int t = 0; t < 6; ++t) acc[t] = 0.f;
    for (int n = lane; n < 500; n += 64) {
      float w = c2W[n];
      const float* gp = g2w + ((b * 32 + c) * 500 + n) * 6;
#pragma unroll
      for (int t = 0; t < 6; ++t) acc[t] += w * gp[t];
    }
#pragma unroll
    for (int t = 0; t < 6; ++t)
      for (int off = 32; off; off >>= 1) acc[t] += __shfl_xor(acc[t], off);
    if (lane == 0) {
#pragma unroll
      for (int t = 0; t < 6; ++t) f2w[(b * 32 + c) * 6 + t] = acc[t];
    }
  }
}

// ---------------- K5b: per-b TATT ----------------
__global__ __launch_bounds__(256) void k_tatt(
    const float* __restrict__ f1w, const float* __restrict__ tatw,
    const float* __restrict__ f2w, const float* __restrict__ tatb, const float* __restrict__ tatv,
    float* __restrict__ lg2w)
{
  __shared__ float mid[192];
  __shared__ float lgt[36];
  int b = blockIdx.x, tid = threadIdx.x;
  if (tid < 192) {
    int t = tid >> 5, c = tid & 31;
    float a = 0.f;
    const float* f1p = f1w + (b * 6 + t) * 500;
    for (int n = 0; n < 500; ++n) a += f1p[n] * tatw[n * 32 + c];
    mid[t * 32 + c] = a;
  }
  __syncthreads();
  if (tid < 36) {
    int t = tid / 6, s = tid - t * 6;
    float a = tatb[t * 6 + s];
    for (int c = 0; c < 32; ++c) a += mid[t * 32 + c] * f2w[(b * 32 + c) * 6 + s];
    lgt[t * 6 + s] = 1.f / (1.f + expf(-a));
  }
  __syncthreads();
  if (tid < 36) {
    int p = tid / 6, s = tid - p * 6;
    float a = 0.f;
#pragma unroll
    for (int t2 = 0; t2 < 6; ++t2) a += tatv[p * 6 + t2] * lgt[t2 * 6 + s];
    lg2w[(b * 6 + p) * 6 + s] = a;
  }
}

// ---------------- K5c: BN1 + softmax -> Tc ----------------
__global__ __launch_bounds__(128) void k_coefs(const float* __restrict__ lg2w,
    const float* __restrict__ bn1g, const float* __restrict__ bn1b, float* __restrict__ tcw) {
  __shared__ float mu[6], iv[6], gg[6], bb[6];
  int tid = threadIdx.x;
  if (tid < 6) {
    float s = 0.f, sq = 0.f;
    for (int b = 0; b < 16; ++b)
      for (int q = 0; q < 6; ++q) {
        float v = lg2w[(b * 6 + q) * 6 + tid];
        s += v; sq += v * v;
      }
    float m = s / 96.f;
    mu[tid] = m;
    iv[tid] = rsqrtf(sq / 96.f - m * m + 1e-5f);
    gg[tid] = bn1g[tid]; bb[tid] = bn1b[tid];
  }
  __syncthreads();
  for (int idx = tid; idx < 96; idx += 128) {
    int b = idx / 6, q = idx - b * 6;
    float v[6], mx = -1e30f;
#pragma unroll
    for (int l = 0; l < 6; ++l) {
      v[l] = (lg2w[(b * 6 + q) * 6 + l] - mu[l]) * iv[l] * gg[l] + bb[l];
      mx = fmaxf(mx, v[l]);
    }
    float tot = 0.f;
#pragma unroll
    for (int l = 0; l < 6; ++l) { v[l] = expf(v[l] - mx); tot += v[l]; }
    float inv = 1.f / tot;
#pragma unroll
    for (int l = 0; l < 6; ++l) tcw[(b * 6 + l) * 6 + q] = v[l] * inv;
  }
}

// ---------------- K6a: xo = leaky(g2@Tc)+res6, per-c sum/sumsq ----------------
__global__ __launch_bounds__(256) void k_xo(const float* __restrict__ g2w,
    const float* __restrict__ res6, const float* __restrict__ tcw,
    float* __restrict__ xow, float* __restrict__ stats) {
  __shared__ float Tcl[36];
  __shared__ float redS[32][8], redQ[32][8];
  int b = blockIdx.x, chunk = blockIdx.y, tid = threadIdx.x;
  if (tid < 36) Tcl[tid] = tcw[b * 36 + tid];
  __syncthreads();
  int c = tid & 31, sub = tid >> 5;
  int n0 = chunk * 50;
  float s = 0.f, sq = 0.f;
  for (int idx = sub; idx < 300; idx += 8) {
    int nl = idx / 6, q = idx - nl * 6;
    int n = n0 + nl;
    int base = ((b * 32 + c) * 500 + n) * 6;
    const float* gp = g2w + base;
    float xv = 0.f;
#pragma unroll
    for (int l = 0; l < 6; ++l) xv += gp[l] * Tcl[l * 6 + q];
    xv = xv > 0.f ? xv : 0.01f * xv;
    xv += res6[base + q];
    xow[base + q] = xv;
    s += xv; sq += xv * xv;
  }
  redS[c][sub] = s; redQ[c][sub] = sq;
  __syncthreads();
  if (sub == 0) {
    float ts = 0.f, tq = 0.f;
#pragma unroll
    for (int k = 0; k < 8; ++k) { ts += redS[c][k]; tq += redQ[c][k]; }
    atomicAdd(&stats[c], ts);
    atomicAdd(&stats[32 + c], tq);
  }
}

// ---------------- K6b: BN2 normalize -> FP32 out ----------------
__global__ __launch_bounds__(256) void k_out(const float* __restrict__ xow,
    const float* __restrict__ stats, const float* __restrict__ g2c, const float* __restrict__ b2c,
    float* __restrict__ out) {
  int base = (blockIdx.x * 256 + threadIdx.x) * 4;
#pragma unroll
  for (int k = 0; k < 4; ++k) {
    int i = base + k;
    int c = (i / 3000) & 31;
    float m = stats[c] * (1.f / 48000.f);
    float var = stats[32 + c] * (1.f / 48000.f) - m * m;
    out[i] = (xow[i] - m) * rsqrtf(var + 1e-5f) * g2c[c] + b2c[c];
  }
}

extern "C" void kernel_launch(void* const* d_in, const int* in_sizes, int n_in,
                              void* d_out, int out_size, void* d_ws, size_t ws_size,
                              hipStream_t stream)
{
  (void)in_sizes; (void)out_size;

  float* ws = (float*)d_ws;
  float* Af   = ws;                 // 250,000 (unused; layout kept)
  float* Wf   = Af + 250000;        // 65,536 (65,322 used)
  float* A2   = Wf + 65536;         // 250,000 (unused; layout kept)
  float* h3x  = A2 + 250000;        // 2,560,000 (B,T,N,32)
  float* z1x  = h3x + 2560000;
  float* z2x  = z1x + 2560000;
  float* z3x  = z2x + 2560000;
  float* z4x  = z3x + 2560000;
  float* res6 = z4x + 2560000;      // 1,536,000
  float* g2w  = res6 + 1536000;     // 1,536,000
  float* f1w  = g2w + 1536000;      // 48,000
  float* f2w  = f1w + 48000;        // 3,072
  float* lg2w = f2w + 3072;         // 576
  float* tcw  = lg2w + 576;         // 576
  float* stats= tcw + 576;          // 64
  float* xow  = z1x;                // reuse z1 region after k_gate
  u16*   Abf  = (u16*)g2w;          // 512x512 bf16 A pack (g2w region dead until k_gate)
  u16*   A2bf = (u16*)(g2w + 131072); // 512x512 bf16 A2 pack
  float* WTp  = g2w + 262144;       // 29,952 folded-weight + frag pack (dead before k_gate)
  u16*   WBu  = (u16*)f1w;          // 10,240 u16 mlpW B-frag pack (f1w region dead until k_f12)
  if (ws_size < (size_t)16489952 * sizeof(float)) return;  // workspace guard

  // converted-weight offsets inside Wf (cumulative over dict inputs 2..28)
  const float* c1B  = Wf + 1024;
  const float* mlpB = Wf + 48512;
  const float* ct1W = Wf + 48576;
  const float* ct1B = Wf + 48636;
  const float* tc1W = Wf + 48642;
  const float* tc2W = Wf + 48674;
  const float* tatw = Wf + 49174;
  const float* tatb = Wf + 65174;
  const float* tatv = Wf + 65210;
  const float* bn1g = Wf + 65246;
  const float* bn1b = Wf + 65252;
  const float* bn2g = Wf + 65258;
  const float* bn2b = Wf + 65290;

  Ptrs ps;
  for (int i = 0; i < 29; ++i) ps.p[i] = (i < n_in) ? d_in[i] : d_in[0];

  k_prep <<<dim3(1398),    256, 0, stream>>>(ps, Wf, Abf, WTp, WBu, stats);
  k_a2m  <<<dim3(16, 8),   256, 0, stream>>>(Abf, A2bf);
  k_front3<<<dim3(2000),   256, 0, stream>>>(ps.p[0], ps.p[25], WTp, c1B, h3x, res6);
  k_z12m <<<dim3(160, 8),  256, 0, stream>>>(h3x, Abf, A2bf, z1x, z2x);
  k_attn2<<<dim3(160, 2),  256, 0, stream>>>(h3x, h3x, z3x);
  k_attn2<<<dim3(160, 2),  256, 0, stream>>>(h3x, z3x, z4x);
  k_gate <<<dim3(16, 16),  256, 0, stream>>>(h3x, z1x, z2x, z3x, z4x,
                                             (const u32*)WBu, mlpB, ct1W, ct1B, g2w);
  k_f12  <<<dim3(316),     256, 0, stream>>>(g2w, tc1W, tc2W, f1w, f2w);
  k_tatt <<<dim3(16),      256, 0, stream>>>(f1w, tatw, f2w, tatb, tatv, lg2w);
  k_coefs<<<dim3(1),       128, 0, stream>>>(lg2w, bn1g, bn1b, tcw);
  k_xo   <<<dim3(16, 10),  256, 0, stream>>>(g2w, res6, tcw, xow, stats);
  k_out  <<<dim3(1500),    256, 0, stream>>>(xow, stats, bn2g, bn2b, (float*)d_out);
}